// Round 9
// baseline (409.502 us; speedup 1.0000x reference)
//
#include <hip/hip_runtime.h>
#include <math.h>

#define B_ 16
#define S_ 1024
#define D_ 256
#define F_ 256
#define T_ 8192
#define ROWS (B_ * S_)  // 16384

typedef __attribute__((ext_vector_type(8))) short short8x;
typedef __attribute__((ext_vector_type(4))) float f32x4;

static __device__ __forceinline__ unsigned short f2bf(float f) {
    unsigned u = __float_as_uint(f);
    unsigned r = (u + 0x7FFFu + ((u >> 16) & 1u)) >> 16;  // round-to-nearest-even
    return (unsigned short)r;
}
static __device__ __forceinline__ float bf2f(unsigned short h) {
    return __uint_as_float(((unsigned)h) << 16);
}

// ============================================================
// K0: weight prep -> FRAGMENT-ORDER layout so conv kernels can read
// MFMA B-fragments as lane-linear 1KB contiguous blocks.
//   frag offset(o_t, cb, k, nt, lane, j) =
//     (((((o_t*8 + cb)*3 + k)*4 + nt)*64) + lane)*8 + j
//   where o = o_t*64 + nt*16 + (lane&15), c = cb*32 + (lane>>4)*8 + j
// Tensors: t0..3 = pp1,ep1,pp2,ep2 (plain bf16); t4..7 = dp1h,dp1l,dp2h,dp2l
// Plus: np_w (K=1) -> hi/lo frag-order planes at wt + 8*196608.
// ============================================================
__global__ __launch_bounds__(256) void wprep_kernel(
    const float* __restrict__ pw1, const float* __restrict__ ew1,
    const float* __restrict__ pw2, const float* __restrict__ ew2,
    const float* __restrict__ dw1, const float* __restrict__ dw2,
    const float* __restrict__ npw,
    unsigned short* __restrict__ wt)
{
    int idx = blockIdx.x * 256 + threadIdx.x;   // 0..65535 -> (o, c)
    int o = idx >> 8, c = idx & 255;
    int o_t = o >> 6, nt = (o >> 4) & 3, lr = o & 15;
    int cbk = c >> 5, hs = (c >> 3) & 3, j = c & 7;
    int lane = hs * 16 + lr;
    size_t fbase = ((size_t)o_t * 8 + cbk) * 3;   // *k later

    const float* srcs[4] = { pw1, ew1, pw2, ew2 };
    #pragma unroll
    for (int t = 0; t < 4; ++t) {
        const float* p = srcs[t] + ((size_t)o * 256 + c) * 3;
        unsigned short* dst = wt + (size_t)t * 196608;
        #pragma unroll
        for (int k = 0; k < 3; ++k) {
            size_t off = (((fbase + k) * 4 + nt) * 64 + lane) * 8 + j;
            dst[off] = f2bf(p[k]);
        }
    }
    const float* dsrc[2] = { dw1, dw2 };
    #pragma unroll
    for (int t = 0; t < 2; ++t) {
        const float* p = dsrc[t] + ((size_t)o * 256 + c) * 3;
        unsigned short* dh = wt + (size_t)(4 + 2 * t) * 196608;
        unsigned short* dl = dh + 196608;
        #pragma unroll
        for (int k = 0; k < 3; ++k) {
            size_t off = (((fbase + k) * 4 + nt) * 64 + lane) * 8 + j;
            float v = p[k];
            unsigned short hi = f2bf(v);
            dh[off] = hi;
            dl[off] = f2bf(v - bf2f(hi));
        }
    }
    // noteproj weight np_w[cin][cout]: o = cout, c = cin (reduction). K=1.
    {
        float v = npw[(size_t)c * 256 + o];
        unsigned short hi = f2bf(v);
        size_t off2 = (((size_t)(o_t * 8 + cbk) * 4 + nt) * 64 + lane) * 8 + j;
        unsigned short* nh = wt + (size_t)8 * 196608;
        unsigned short* nl = nh + 65536;
        nh[off2] = hi;
        nl[off2] = f2bf(v - bf2f(hi));
    }
}

// ============================================================
// K1: x' = x + note_pitch @ np_w + np_b via split-bf16 MFMA
// (3-term: hi*hi + hi*lo + lo*hi). A = note loaded fp32, split
// in-register. Epilogue: LDS transpose + fused "+x" add, fp32 out.
// grid (64, 4), 256 threads; 256-row x 64-col tiles, 64 rows/wave.
// ============================================================
__global__ __launch_bounds__(256) void noteproj_mfma_kernel(
    const float* __restrict__ note,
    const unsigned short* __restrict__ wh, const unsigned short* __restrict__ wl,
    const float* __restrict__ x, const float* __restrict__ bias,
    float* __restrict__ xp, unsigned* __restrict__ red)
{
    if (blockIdx.x == 0 && blockIdx.y == 0 && threadIdx.x == 0) {
        red[0] = 0u;            // max ||xn||
        red[1] = 0x7F7FFFFFu;   // min ||x'||  (FLT_MAX bits)
        red[2] = 0u;            // max ||x'||
    }
    __shared__ __align__(16) char smem[36864];   // 128 x 72 f32 epilogue buffer
    const int tid = threadIdx.x;
    const int o0 = blockIdx.y << 6;
    const int R0 = blockIdx.x << 8;
    const int wave = tid >> 6, lane = tid & 63;
    const int lm = lane & 15, lk8 = (lane >> 4) << 3;
    const int q4 = (lane >> 4) << 2;
    const int wr = wave << 6;
    f32x4 acc[4][4] = {};
    unsigned aoff[4];
    #pragma unroll
    for (int st = 0; st < 4; ++st)
        aoff[st] = (unsigned)(R0 + wr + (st << 4) + lm) * D_ + lk8;
    const unsigned short* whp = wh + (size_t)(o0 >> 6) * 16384 + (size_t)lane * 8;
    const unsigned short* wlp = wl + (size_t)(o0 >> 6) * 16384 + (size_t)lane * 8;
    for (int c0 = 0; c0 < D_; c0 += 32) {
        const int cbi = c0 >> 5;
        short8x ah[4], al[4];
        #pragma unroll
        for (int st = 0; st < 4; ++st) {
            float4 va = *(const float4*)(note + aoff[st] + c0);
            float4 vb = *(const float4*)(note + aoff[st] + c0 + 4);
            float vv[8] = { va.x, va.y, va.z, va.w, vb.x, vb.y, vb.z, vb.w };
            #pragma unroll
            for (int e = 0; e < 8; ++e) {
                unsigned short hi = f2bf(vv[e]);
                ah[st][e] = (short)hi;
                al[st][e] = (short)f2bf(vv[e] - bf2f(hi));
            }
        }
        const unsigned short* bph = whp + (size_t)(cbi * 4) * 512;
        const unsigned short* bpl = wlp + (size_t)(cbi * 4) * 512;
        #pragma unroll
        for (int nt = 0; nt < 4; ++nt) {
            short8x bh = *(const short8x*)(const void*)(bph + nt * 512);
            short8x bl = *(const short8x*)(const void*)(bpl + nt * 512);
            #pragma unroll
            for (int st = 0; st < 4; ++st) {
                acc[st][nt] = __builtin_amdgcn_mfma_f32_16x16x32_bf16(ah[st], bh, acc[st][nt], 0, 0, 0);
                acc[st][nt] = __builtin_amdgcn_mfma_f32_16x16x32_bf16(ah[st], bl, acc[st][nt], 0, 0, 0);
                acc[st][nt] = __builtin_amdgcn_mfma_f32_16x16x32_bf16(al[st], bh, acc[st][nt], 0, 0, 0);
            }
        }
    }
    // ---- epilogue: acc + bias, LDS transpose, + x, fp32 store ----
    float bvv[4];
    #pragma unroll
    for (int nt = 0; nt < 4; ++nt) bvv[nt] = bias[o0 + (nt << 4) + lm];
    const int hw = wr >> 7, base = wr & 127;
    float* Lf = (float*)smem;
    #pragma unroll
    for (int h = 0; h < 2; ++h) {
        if (h) __syncthreads();
        if (hw == h) {
            #pragma unroll
            for (int nt = 0; nt < 4; ++nt)
                #pragma unroll
                for (int st = 0; st < 4; ++st)
                    #pragma unroll
                    for (int rg = 0; rg < 4; ++rg) {
                        int lrow = base + (st << 4) + q4 + rg;
                        int lcol = (nt << 4) + lm;
                        Lf[lrow * 72 + lcol] = acc[st][nt][rg] + bvv[nt];
                    }
        }
        __syncthreads();
        #pragma unroll
        for (int q = 0; q < 8; ++q) {
            int flat = (q << 8) + tid;
            int rrow = flat >> 4, u4 = flat & 15;
            size_t off = ((size_t)(R0 + (h << 7) + rrow)) * D_ + o0 + (u4 << 2);
            float4 lv = *(const float4*)(const void*)&Lf[rrow * 72 + (u4 << 2)];
            float4 xv = *(const float4*)(x + off);
            float4 ov;
            ov.x = lv.x + xv.x; ov.y = lv.y + xv.y;
            ov.z = lv.z + xv.z; ov.w = lv.w + xv.w;
            *(float4*)(xp + off) = ov;
        }
    }
}

// ============================================================
// K2: layernorm + norms + bf16 copies. 1 wave = 1 row.
// ============================================================
__global__ __launch_bounds__(256) void rowstats_kernel(
    const float* __restrict__ xp, const float* __restrict__ g, const float* __restrict__ bb,
    unsigned short* __restrict__ xnh, unsigned short* __restrict__ xnl,
    float* __restrict__ nxn, float* __restrict__ nx,
    unsigned short* __restrict__ xpb)
{
    int row = blockIdx.x * 4 + (threadIdx.x >> 6);
    int lane = threadIdx.x & 63;
    float4 v = ((const float4*)(xp + (size_t)row * D_))[lane];
    ushort4 bv4;
    bv4.x = f2bf(v.x); bv4.y = f2bf(v.y); bv4.z = f2bf(v.z); bv4.w = f2bf(v.w);
    ((ushort4*)xpb)[(size_t)row * 64 + lane] = bv4;

    float s = v.x + v.y + v.z + v.w;
    float sq = v.x * v.x + v.y * v.y + v.z * v.z + v.w * v.w;
    #pragma unroll
    for (int m = 32; m; m >>= 1) { s += __shfl_xor(s, m); sq += __shfl_xor(sq, m); }
    float mean = s * (1.f / 256.f);
    float var = sq * (1.f / 256.f) - mean * mean;
    float rs = rsqrtf(var + 1e-5f);
    float4 gv = ((const float4*)g)[lane];
    float4 bv = ((const float4*)bb)[lane];
    float4 o;
    o.x = gv.x * (v.x - mean) * rs + bv.x;
    o.y = gv.y * (v.y - mean) * rs + bv.y;
    o.z = gv.z * (v.z - mean) * rs + bv.z;
    o.w = gv.w * (v.w - mean) * rs + bv.w;
    ushort4 h4, l4;
    h4.x = f2bf(o.x); l4.x = f2bf(o.x - bf2f(h4.x));
    h4.y = f2bf(o.y); l4.y = f2bf(o.y - bf2f(h4.y));
    h4.z = f2bf(o.z); l4.z = f2bf(o.z - bf2f(h4.z));
    h4.w = f2bf(o.w); l4.w = f2bf(o.w - bf2f(h4.w));
    ((ushort4*)xnh)[(size_t)row * 64 + lane] = h4;
    ((ushort4*)xnl)[(size_t)row * 64 + lane] = l4;

    float q = o.x * o.x + o.y * o.y + o.z * o.z + o.w * o.w;
    #pragma unroll
    for (int m = 32; m; m >>= 1) q += __shfl_xor(q, m);
    if (lane == 0) { nxn[row] = sqrtf(q); nx[row] = sqrtf(sq); }
}

// ============================================================
// K3: fast global reduce via uint-monotonic atomics (positive floats)
// ============================================================
__global__ __launch_bounds__(256) void reduce_fast_kernel(
    const float* __restrict__ nxn, const float* __restrict__ nx, unsigned* __restrict__ red)
{
    int tid = threadIdx.x;
    int lane = tid & 63, wave = tid >> 6;
    float mxn = 0.f, mnx = 3.0e38f, mxx = 0.f;
    for (int i = blockIdx.x * 256 + tid; i < ROWS; i += 32 * 256) {
        mxn = fmaxf(mxn, nxn[i]);
        float v = nx[i];
        mnx = fminf(mnx, v);
        mxx = fmaxf(mxx, v);
    }
    #pragma unroll
    for (int m = 32; m; m >>= 1) {
        mxn = fmaxf(mxn, __shfl_xor(mxn, m));
        mnx = fminf(mnx, __shfl_xor(mnx, m));
        mxx = fmaxf(mxx, __shfl_xor(mxx, m));
    }
    __shared__ float a0[4], a1[4], a2[4];
    if (lane == 0) { a0[wave] = mxn; a1[wave] = mnx; a2[wave] = mxx; }
    __syncthreads();
    if (tid == 0) {
        #pragma unroll
        for (int w2 = 1; w2 < 4; ++w2) {
            mxn = fmaxf(mxn, a0[w2]); mnx = fminf(mnx, a1[w2]); mxx = fmaxf(mxx, a2[w2]);
        }
        atomicMax(&red[0], __float_as_uint(mxn));
        atomicMin(&red[1], __float_as_uint(mnx));
        atomicMax(&red[2], __float_as_uint(mxx));
    }
}

// ============================================================
// K4: LDS-free conv stage (byte-identical to R8-passing version).
//   z=0: dp split-bf16, 256-row tile, 64 rows/wave (x<64 active)
//   z=1,2: pp/ep plain bf16, 256-row tile, 64 rows/wave
// grid (128, 4, 3), 256 threads.
// ============================================================
struct ConvAll {
    const unsigned short* dp_in_hi; const unsigned short* dp_in_lo;   // [B*S][256]
    const unsigned short* dp_wt_hi; const unsigned short* dp_wt_lo;   // frag-order
    const float* dp_bias;
    unsigned short* dp_out_hi; unsigned short* dp_out_lo;  // stage1 (bfout=1)
    float* dp_out_f;                                        // stage2 (bfout=0)
    const unsigned short* inb[2];
    const unsigned short* wt[2];     // frag-order
    const float* bias[2];
    void* out[2];
    int bfout;
};

__global__ __launch_bounds__(256) void convall_kernel(ConvAll cb)
{
    __shared__ __align__(16) char smem[36864];   // 128 x 72 f32 epilogue buffer
    const int tid = threadIdx.x;
    const int z = blockIdx.z;
    const int o0 = blockIdx.y << 6;
    const int wave = tid >> 6, lane = tid & 63;
    const int lm = lane & 15, lk8 = (lane >> 4) << 3;
    const int q4 = (lane >> 4) << 2;

    if (z == 0) {
        // ---------------- dp split-bf16 path: 256-row tile, 64 rows/wave ----------------
        if (blockIdx.x >= 64) return;           // whole block exits: no barrier hazard
        const int b = blockIdx.x >> 2;
        const int S0 = (blockIdx.x & 3) << 8;   // 0,256,512,768
        const int wr = wave << 6;               // wave's first row (0,64,128,192)
        f32x4 acc[4][4] = {};
        unsigned aoff[4][3]; bool aok[4][3];
        #pragma unroll
        for (int st = 0; st < 4; ++st)
            #pragma unroll
            for (int k = 0; k < 3; ++k) {
                int srow = S0 + wr + (st << 4) + lm + k - 1;
                aok[st][k] = (srow >= 0) && (srow < S_);
                int sr = srow < 0 ? 0 : (srow >= S_ ? S_ - 1 : srow);
                aoff[st][k] = (unsigned)(b * S_ + sr) * D_ + lk8;
            }
        const unsigned short* ih = cb.dp_in_hi;
        const unsigned short* il = cb.dp_in_lo;
        const unsigned short* wh = cb.dp_wt_hi + (size_t)(o0 >> 6) * 49152 + (size_t)lane * 8;
        const unsigned short* wl = cb.dp_wt_lo + (size_t)(o0 >> 6) * 49152 + (size_t)lane * 8;
        for (int c0 = 0; c0 < D_; c0 += 32) {
            const int cbi = c0 >> 5;
            #pragma unroll
            for (int k = 0; k < 3; ++k) {
                uint4 ah4[4], al4[4];
                #pragma unroll
                for (int st = 0; st < 4; ++st) {
                    uint4 vh = make_uint4(0u, 0u, 0u, 0u);
                    uint4 vl = make_uint4(0u, 0u, 0u, 0u);
                    if (aok[st][k]) {
                        unsigned off = aoff[st][k] + c0;
                        vh = *(const uint4*)(const void*)(ih + off);
                        vl = *(const uint4*)(const void*)(il + off);
                    }
                    ah4[st] = vh; al4[st] = vl;
                }
                const unsigned short* bph = wh + (size_t)((cbi * 3 + k) * 4) * 512;
                const unsigned short* bpl = wl + (size_t)((cbi * 3 + k) * 4) * 512;
                #pragma unroll
                for (int nt = 0; nt < 4; ++nt) {
                    short8x bh = *(const short8x*)(const void*)(bph + nt * 512);
                    short8x bl = *(const short8x*)(const void*)(bpl + nt * 512);
                    #pragma unroll
                    for (int st = 0; st < 4; ++st) {
                        short8x ah = *(short8x*)&ah4[st];
                        short8x al = *(short8x*)&al4[st];
                        acc[st][nt] = __builtin_amdgcn_mfma_f32_16x16x32_bf16(ah, bh, acc[st][nt], 0, 0, 0);
                        acc[st][nt] = __builtin_amdgcn_mfma_f32_16x16x32_bf16(ah, bl, acc[st][nt], 0, 0, 0);
                        acc[st][nt] = __builtin_amdgcn_mfma_f32_16x16x32_bf16(al, bh, acc[st][nt], 0, 0, 0);
                    }
                }
            }
        }
        // ---- dp epilogue: 256 rows via two 128-row halves ----
        float bvv[4];
        #pragma unroll
        for (int nt = 0; nt < 4; ++nt) bvv[nt] = cb.dp_bias[o0 + (nt << 4) + lm];
        const int hw = wr >> 7;        // 0 for waves 0,1; 1 for waves 2,3
        const int base = wr & 127;     // 0 or 64 within the half
        if (cb.bfout) {
            unsigned short* L = (unsigned short*)smem;           // [128][72] ushorts
            #pragma unroll
            for (int pass = 0; pass < 2; ++pass) {
                unsigned short* outp = pass ? cb.dp_out_lo : cb.dp_out_hi;
                #pragma unroll
                for (int h = 0; h < 2; ++h) {
                    if (pass | h) __syncthreads();
                    if (hw == h) {
                        #pragma unroll
                        for (int nt = 0; nt < 4; ++nt)
                            #pragma unroll
                            for (int st = 0; st < 4; ++st)
                                #pragma unroll
                                for (int rg = 0; rg < 4; ++rg) {
                                    int lrow = base + (st << 4) + q4 + rg;
                                    int lcol = (nt << 4) + lm;
                                    float v = fmaxf(acc[st][nt][rg] + bvv[nt], 0.f);
                                    unsigned short hi = f2bf(v);
                                    L[lrow * 72 + lcol] = pass ? f2bf(v - bf2f(hi)) : hi;
                                }
                    }
                    __syncthreads();
                    #pragma unroll
                    for (int q = 0; q < 4; ++q) {
                        int flat = (q << 8) + tid;
                        int rrow = flat >> 3, u = flat & 7;
                        uint4 val = *(const uint4*)(const void*)&L[rrow * 72 + (u << 3)];
                        *(uint4*)(void*)(outp + ((size_t)(b * S_ + S0 + (h << 7) + rrow)) * D_ + o0 + (u << 3)) = val;
                    }
                }
            }
        } else {
            float* Lf = (float*)smem;                            // [128][72] floats
            #pragma unroll
            for (int h = 0; h < 2; ++h) {
                if (h) __syncthreads();
                if (hw == h) {
                    #pragma unroll
                    for (int nt = 0; nt < 4; ++nt)
                        #pragma unroll
                        for (int st = 0; st < 4; ++st)
                            #pragma unroll
                            for (int rg = 0; rg < 4; ++rg) {
                                int lrow = base + (st << 4) + q4 + rg;
                                int lcol = (nt << 4) + lm;
                                Lf[lrow * 72 + lcol] = fmaxf(acc[st][nt][rg] + bvv[nt], 0.f);
                            }
                }
                __syncthreads();
                #pragma unroll
                for (int q = 0; q < 8; ++q) {
                    int flat = (q << 8) + tid;
                    int rrow = flat >> 4, u4 = flat & 15;
                    uint4 val = *(const uint4*)(const void*)&Lf[rrow * 72 + (u4 << 2)];
                    *(uint4*)(void*)(cb.dp_out_f + ((size_t)(b * S_ + S0 + (h << 7) + rrow)) * D_ + o0 + (u4 << 2)) = val;
                }
            }
        }
    } else {
        // ---------------- pp/ep path: 256-row tile, 64 rows/wave (R6/R7-exact) ----------------
        if (blockIdx.x >= 64) return;           // whole block exits: no barrier hazard
        const int z1 = z - 1;
        const int b = blockIdx.x >> 2;
        const int S0 = (blockIdx.x & 3) << 8;   // 0,256,512,768
        const int wr = wave << 6;               // wave's first row (0,64,128,192)
        f32x4 acc[4][4] = {};
        unsigned aoff[4][3]; bool aok[4][3];
        #pragma unroll
        for (int st = 0; st < 4; ++st)
            #pragma unroll
            for (int k = 0; k < 3; ++k) {
                int srow = S0 + wr + (st << 4) + lm + k - 1;
                aok[st][k] = (srow >= 0) && (srow < S_);
                int sr = srow < 0 ? 0 : (srow >= S_ ? S_ - 1 : srow);
                aoff[st][k] = (unsigned)(b * S_ + sr) * D_ + lk8;
            }
        const unsigned short* inp = cb.inb[z1];
        const unsigned short* wp = cb.wt[z1] + (size_t)(o0 >> 6) * 49152 + (size_t)lane * 8;
        for (int c0 = 0; c0 < D_; c0 += 32) {
            const int cbi = c0 >> 5;
            uint4 pa[4][3];
            #pragma unroll
            for (int st = 0; st < 4; ++st)
                #pragma unroll
                for (int k = 0; k < 3; ++k) {
                    uint4 v = make_uint4(0u, 0u, 0u, 0u);
                    if (aok[st][k]) v = *(const uint4*)(const void*)(inp + aoff[st][k] + c0);
                    pa[st][k] = v;
                }
            #pragma unroll
            for (int k = 0; k < 3; ++k) {
                const unsigned short* bp = wp + (size_t)((cbi * 3 + k) * 4) * 512;
                short8x a0 = *(short8x*)&pa[0][k];
                short8x a1 = *(short8x*)&pa[1][k];
                short8x a2 = *(short8x*)&pa[2][k];
                short8x a3 = *(short8x*)&pa[3][k];
                #pragma unroll
                for (int nt = 0; nt < 4; ++nt) {
                    short8x bf = *(const short8x*)(const void*)(bp + nt * 512);
                    acc[0][nt] = __builtin_amdgcn_mfma_f32_16x16x32_bf16(a0, bf, acc[0][nt], 0, 0, 0);
                    acc[1][nt] = __builtin_amdgcn_mfma_f32_16x16x32_bf16(a1, bf, acc[1][nt], 0, 0, 0);
                    acc[2][nt] = __builtin_amdgcn_mfma_f32_16x16x32_bf16(a2, bf, acc[2][nt], 0, 0, 0);
                    acc[3][nt] = __builtin_amdgcn_mfma_f32_16x16x32_bf16(a3, bf, acc[3][nt], 0, 0, 0);
                }
            }
        }
        // ---- pp/ep epilogue: two 128-row passes ----
        float bvv[4];
        #pragma unroll
        for (int nt = 0; nt < 4; ++nt) bvv[nt] = cb.bias[z1][o0 + (nt << 4) + lm];
        const int hw = wr >> 7;        // 0 for waves 0,1; 1 for waves 2,3
        const int base = wr & 127;     // 0 or 64 within the half
        if (cb.bfout) {
            unsigned short* L = (unsigned short*)smem;           // [128][72] ushorts
            unsigned short* outp = (unsigned short*)cb.out[z1];
            #pragma unroll
            for (int h = 0; h < 2; ++h) {
                if (h) __syncthreads();
                if (hw == h) {
                    #pragma unroll
                    for (int nt = 0; nt < 4; ++nt)
                        #pragma unroll
                        for (int st = 0; st < 4; ++st)
                            #pragma unroll
                            for (int rg = 0; rg < 4; ++rg) {
                                int lrow = base + (st << 4) + q4 + rg;
                                int lcol = (nt << 4) + lm;
                                L[lrow * 72 + lcol] = f2bf(fmaxf(acc[st][nt][rg] + bvv[nt], 0.f));
                            }
                }
                __syncthreads();
                #pragma unroll
                for (int q = 0; q < 4; ++q) {
                    int flat = (q << 8) + tid;
                    int rrow = flat >> 3, u = flat & 7;
                    uint4 val = *(const uint4*)(const void*)&L[rrow * 72 + (u << 3)];
                    *(uint4*)(void*)(outp + ((size_t)(b * S_ + S0 + (h << 7) + rrow)) * D_ + o0 + (u << 3)) = val;
                }
            }
        } else {
            float* Lf = (float*)smem;                            // [128][72] floats
            float* outp = (float*)cb.out[z1];
            #pragma unroll
            for (int h = 0; h < 2; ++h) {
                if (h) __syncthreads();
                if (hw == h) {
                    #pragma unroll
                    for (int nt = 0; nt < 4; ++nt)
                        #pragma unroll
                        for (int st = 0; st < 4; ++st)
                            #pragma unroll
                            for (int rg = 0; rg < 4; ++rg) {
                                int lrow = base + (st << 4) + q4 + rg;
                                int lcol = (nt << 4) + lm;
                                Lf[lrow * 72 + lcol] = fmaxf(acc[st][nt][rg] + bvv[nt], 0.f);
                            }
                }
                __syncthreads();
                #pragma unroll
                for (int q = 0; q < 8; ++q) {
                    int flat = (q << 8) + tid;
                    int rrow = flat >> 4, u4 = flat & 15;
                    uint4 val = *(const uint4*)(const void*)&Lf[rrow * 72 + (u4 << 2)];
                    *(uint4*)(void*)(outp + ((size_t)(b * S_ + S0 + (h << 7) + rrow)) * D_ + o0 + (u4 << 2)) = val;
                }
            }
        }
    }
}

// ============================================================
// K5: fused final linears + epilogues. 1 wave = 1 row.
// ============================================================
__global__ __launch_bounds__(256) void linfused_kernel(
    const float* __restrict__ h2dp, const float* __restrict__ h2pp, const float* __restrict__ h2ep,
    const float* __restrict__ dp_wl, const float* __restrict__ dp_bl,
    const float* __restrict__ pp_wl, const float* __restrict__ pp_bl,
    const float* __restrict__ ep_wl, const float* __restrict__ ep_bl,
    const float* __restrict__ nxn, const float* __restrict__ nx, const unsigned* __restrict__ red,
    float* __restrict__ o_logdur, float* __restrict__ o_dur, float* __restrict__ durf,
    float* __restrict__ o_pitch, float* __restrict__ o_energy)
{
    int row = blockIdx.x * 4 + (threadIdx.x >> 6);
    int lane = threadIdx.x & 63;
    float4 hd = ((const float4*)(h2dp + (size_t)row * F_))[lane];
    float4 wd = ((const float4*)dp_wl)[lane];
    float ad = hd.x * wd.x + hd.y * wd.y + hd.z * wd.z + hd.w * wd.w;

    float4 he = ((const float4*)(h2ep + (size_t)row * F_))[lane];
    float4 we = ((const float4*)ep_wl)[lane];
    float ae = he.x * we.x + he.y * we.y + he.z * we.z + he.w * we.w;

    float4 hp = ((const float4*)(h2pp + (size_t)row * F_))[lane];
    float hv[4] = { hp.x, hp.y, hp.z, hp.w };
    float a0 = 0.f, a1 = 0.f, a2 = 0.f;
    #pragma unroll
    for (int u = 0; u < 4; ++u) {
        int c = lane * 4 + u;
        a0 = fmaf(hv[u], pp_wl[c * 3 + 0], a0);
        a1 = fmaf(hv[u], pp_wl[c * 3 + 1], a1);
        a2 = fmaf(hv[u], pp_wl[c * 3 + 2], a2);
    }
    #pragma unroll
    for (int m = 32; m; m >>= 1) {
        ad += __shfl_xor(ad, m);
        ae += __shfl_xor(ae, m);
        a0 += __shfl_xor(a0, m); a1 += __shfl_xor(a1, m); a2 += __shfl_xor(a2, m);
    }
    if (lane == 0) {
        float base = ad + dp_bl[0];
        float es = 0.8f + 0.4f * (nxn[row] / __uint_as_float(red[0]));
        int s = row & (S_ - 1);
        float ps = 1.0f + 0.1f * ((float)s * (1.f / (float)S_));
        float ld = base * es * ps;
        float d = expf(ld);
        o_logdur[row] = ld;
        o_dur[row] = d;
        durf[row] = d;
        float p0 = a0 + pp_bl[0], p1 = a1 + pp_bl[1], p2 = a2 + pp_bl[2];
        float mn = __uint_as_float(red[1]), mx = __uint_as_float(red[2]);
        float en = (nx[row] - mn) / (mx - mn + 1e-8f);
        float f0s = 100.f + 400.f * en;
        float f0b = expf(p0) * f0s * (1.f / 220.f);
        o_pitch[(size_t)row * 3 + 0] = logf(f0b + 1e-8f);
        o_pitch[(size_t)row * 3 + 1] = p1;
        o_pitch[(size_t)row * 3 + 2] = p2;
        o_energy[row] = ae + ep_bl[0];
    }
}

// ============================================================
// K6: per-batch round->cumsum->clip->searchsorted + mel mask
// (R1-passing version: searches amortized 8/thread across 1024 threads)
// ============================================================
__global__ __launch_bounds__(1024) void regulate_kernel(
    const float* __restrict__ durf, int* __restrict__ idxbuf, float* __restrict__ mask)
{
    __shared__ int cum[S_];
    int b = blockIdx.x;
    int t = threadIdx.x;
    int d = (int)rintf(durf[b * S_ + t]);
    cum[t] = d;
    __syncthreads();
    for (int off = 1; off < S_; off <<= 1) {
        int v = (t >= off) ? cum[t - off] : 0;
        __syncthreads();
        cum[t] += v;
        __syncthreads();
    }
    cum[t] = min(cum[t], T_);
    __syncthreads();
    int total = cum[S_ - 1];
    for (int t0 = t; t0 < T_; t0 += S_) {
        int lo = 0, hi = S_;
        while (lo < hi) {
            int mid = (lo + hi) >> 1;
            if (cum[mid] <= t0) lo = mid + 1; else hi = mid;
        }
        int id = min(lo, S_ - 1);
        bool masked = (t0 >= total);
        idxbuf[b * T_ + t0] = masked ? -1 : id;
        mask[(size_t)b * T_ + t0] = masked ? 1.f : 0.f;
    }
}

// ============================================================
// K7: expanded gather. 1 wave = 1 (b,t) row, float4/lane
// (R1-passing version: pure streaming gather)
// ============================================================
__global__ __launch_bounds__(256) void expand_kernel(
    const float* __restrict__ xp, const int* __restrict__ idxbuf, float* __restrict__ expd)
{
    int row = blockIdx.x * 4 + (threadIdx.x >> 6);
    int lane = threadIdx.x & 63;
    int id = idxbuf[row];
    int b = row >> 13;
    float4 v = make_float4(0.f, 0.f, 0.f, 0.f);
    if (id >= 0)
        v = ((const float4*)(xp + ((size_t)(b * S_ + id)) * D_))[lane];
    ((float4*)(expd + (size_t)row * D_))[lane] = v;
}

// ============================================================
extern "C" void kernel_launch(void* const* d_in, const int* in_sizes, int n_in,
                              void* d_out, int out_size, void* d_ws, size_t ws_size,
                              hipStream_t stream) {
    const float* x     = (const float*)d_in[0];
    const float* note  = (const float*)d_in[2];
    const float* ln_g  = (const float*)d_in[3];
    const float* ln_b  = (const float*)d_in[4];
    const float* dp_w1 = (const float*)d_in[5];
    const float* dp_b1 = (const float*)d_in[6];
    const float* dp_w2 = (const float*)d_in[7];
    const float* dp_b2 = (const float*)d_in[8];
    const float* dp_wl = (const float*)d_in[9];
    const float* dp_bl = (const float*)d_in[10];
    const float* pp_w1 = (const float*)d_in[11];
    const float* pp_b1 = (const float*)d_in[12];
    const float* pp_w2 = (const float*)d_in[13];
    const float* pp_b2 = (const float*)d_in[14];
    const float* pp_wl = (const float*)d_in[15];
    const float* pp_bl = (const float*)d_in[16];
    const float* ep_w1 = (const float*)d_in[17];
    const float* ep_b1 = (const float*)d_in[18];
    const float* ep_w2 = (const float*)d_in[19];
    const float* ep_b2 = (const float*)d_in[20];
    const float* ep_wl = (const float*)d_in[21];
    const float* ep_bl = (const float*)d_in[22];
    const float* np_w  = (const float*)d_in[23];
    const float* np_b  = (const float*)d_in[24];

    // d_out: logdur | dur | pitch | energy | expanded | melmask
    float* o_logdur = (float*)d_out;
    float* o_dur    = o_logdur + ROWS;
    float* o_pitch  = o_dur + ROWS;
    float* o_energy = o_pitch + ROWS * 3;
    float* o_exp    = o_energy + ROWS;
    float* o_mask   = o_exp + (size_t)B_ * T_ * D_;

    // intermediates inside the expanded region (rewritten last by expand)
    const size_t CH = (size_t)ROWS * D_;      // 4,194,304 floats
    float* h2_dp = o_exp + 0 * CH;
    float* h2_pp = o_exp + 1 * CH;
    float* h2_ep = o_exp + 2 * CH;
    unsigned short* h1_ppb  = (unsigned short*)(o_exp + 3 * CH);            // CH bf16
    unsigned short* h1_epb  = (unsigned short*)(o_exp + 3 * CH + CH / 2);   // CH bf16
    unsigned short* xp_bf   = (unsigned short*)(o_exp + 4 * CH);            // CH bf16
    unsigned short* xn_hi   = (unsigned short*)(o_exp + 4 * CH + CH / 2);   // CH bf16
    unsigned short* xn_lo   = (unsigned short*)(o_exp + 5 * CH);            // CH bf16
    unsigned short* h1dp_hi = (unsigned short*)(o_exp + 5 * CH + CH / 2);   // CH bf16
    unsigned short* h1dp_lo = (unsigned short*)(o_exp + 6 * CH);            // CH bf16
    unsigned short* wt      = (unsigned short*)(o_exp + 6 * CH + CH / 2);   // 8*196608 + 2*65536 bf16
    unsigned short* wt_pp1  = wt;
    unsigned short* wt_ep1  = wt + 196608;
    unsigned short* wt_pp2  = wt + 2 * 196608;
    unsigned short* wt_ep2  = wt + 3 * 196608;
    unsigned short* wt_dp1h = wt + 4 * 196608;
    unsigned short* wt_dp1l = wt + 5 * 196608;
    unsigned short* wt_dp2h = wt + 6 * 196608;
    unsigned short* wt_dp2l = wt + 7 * 196608;
    unsigned short* wt_nph  = wt + 8 * 196608;
    unsigned short* wt_npl  = wt_nph + 65536;

    // d_ws: xprime | norm_xn | norm_x | red | durf | idxbuf
    float* ws_f    = (float*)d_ws;
    float* xprime  = ws_f;
    float* norm_xn = ws_f + CH;
    float* norm_x  = norm_xn + ROWS;
    unsigned* red  = (unsigned*)(norm_x + ROWS);
    float* durf    = (float*)(red + 4);
    int*   idxbuf  = (int*)(durf + ROWS);

    wprep_kernel<<<256, 256, 0, stream>>>(pp_w1, ep_w1, pp_w2, ep_w2, dp_w1, dp_w2, np_w, wt);
    noteproj_mfma_kernel<<<dim3(64, 4), 256, 0, stream>>>(note, wt_nph, wt_npl, x, np_b, xprime, red);
    rowstats_kernel<<<ROWS / 4, 256, 0, stream>>>(xprime, ln_g, ln_b, xn_hi, xn_lo, norm_xn, norm_x, xp_bf);
    reduce_fast_kernel<<<32, 256, 0, stream>>>(norm_xn, norm_x, red);

    dim3 cgrid(B_ * (S_ / 128), F_ / 64, 3);
    ConvAll s1;
    s1.dp_in_hi = xn_hi;   s1.dp_in_lo = xn_lo;
    s1.dp_wt_hi = wt_dp1h; s1.dp_wt_lo = wt_dp1l;
    s1.dp_bias = dp_b1;
    s1.dp_out_hi = h1dp_hi; s1.dp_out_lo = h1dp_lo; s1.dp_out_f = nullptr;
    s1.inb[0] = xp_bf;  s1.wt[0] = wt_pp1; s1.bias[0] = pp_b1; s1.out[0] = (void*)h1_ppb;
    s1.inb[1] = xp_bf;  s1.wt[1] = wt_ep1; s1.bias[1] = ep_b1; s1.out[1] = (void*)h1_epb;
    s1.bfout = 1;
    convall_kernel<<<cgrid, 256, 0, stream>>>(s1);

    ConvAll s2;
    s2.dp_in_hi = h1dp_hi; s2.dp_in_lo = h1dp_lo;
    s2.dp_wt_hi = wt_dp2h; s2.dp_wt_lo = wt_dp2l;
    s2.dp_bias = dp_b2;
    s2.dp_out_hi = nullptr; s2.dp_out_lo = nullptr; s2.dp_out_f = h2_dp;
    s2.inb[0] = h1_ppb; s2.wt[0] = wt_pp2; s2.bias[0] = pp_b2; s2.out[0] = (void*)h2_pp;
    s2.inb[1] = h1_epb; s2.wt[1] = wt_ep2; s2.bias[1] = ep_b2; s2.out[1] = (void*)h2_ep;
    s2.bfout = 0;
    convall_kernel<<<cgrid, 256, 0, stream>>>(s2);

    linfused_kernel<<<ROWS / 4, 256, 0, stream>>>(h2_dp, h2_pp, h2_ep,
        dp_wl, dp_bl, pp_wl, pp_bl, ep_wl, ep_bl,
        norm_xn, norm_x, red, o_logdur, o_dur, durf, o_pitch, o_energy);

    regulate_kernel<<<B_, 1024, 0, stream>>>(durf, idxbuf, o_mask);
    expand_kernel<<<(B_ * T_) / 4, 256, 0, stream>>>(xprime, idxbuf, o_exp);
}

// Round 10
// 404.597 us; speedup vs baseline: 1.0121x; 1.0121x over previous
//
#include <hip/hip_runtime.h>
#include <math.h>

#define B_ 16
#define S_ 1024
#define D_ 256
#define F_ 256
#define T_ 8192
#define ROWS (B_ * S_)  // 16384

typedef __attribute__((ext_vector_type(8))) short short8x;
typedef __attribute__((ext_vector_type(4))) float f32x4;

static __device__ __forceinline__ unsigned short f2bf(float f) {
    unsigned u = __float_as_uint(f);
    unsigned r = (u + 0x7FFFu + ((u >> 16) & 1u)) >> 16;  // round-to-nearest-even
    return (unsigned short)r;
}
static __device__ __forceinline__ float bf2f(unsigned short h) {
    return __uint_as_float(((unsigned)h) << 16);
}

// ============================================================
// K0: weight prep -> FRAGMENT-ORDER layout (R8-exact).
// Tensors: t0..3 = pp1,ep1,pp2,ep2 (plain bf16); t4..7 = dp1h,dp1l,dp2h,dp2l
// ============================================================
__global__ __launch_bounds__(256) void wprep_kernel(
    const float* __restrict__ pw1, const float* __restrict__ ew1,
    const float* __restrict__ pw2, const float* __restrict__ ew2,
    const float* __restrict__ dw1, const float* __restrict__ dw2,
    unsigned short* __restrict__ wt)
{
    int idx = blockIdx.x * 256 + threadIdx.x;   // 0..65535 -> (o, c)
    int o = idx >> 8, c = idx & 255;
    int o_t = o >> 6, nt = (o >> 4) & 3, lr = o & 15;
    int cbk = c >> 5, hs = (c >> 3) & 3, j = c & 7;
    int lane = hs * 16 + lr;
    size_t fbase = ((size_t)o_t * 8 + cbk) * 3;   // *k later

    const float* srcs[4] = { pw1, ew1, pw2, ew2 };
    #pragma unroll
    for (int t = 0; t < 4; ++t) {
        const float* p = srcs[t] + ((size_t)o * 256 + c) * 3;
        unsigned short* dst = wt + (size_t)t * 196608;
        #pragma unroll
        for (int k = 0; k < 3; ++k) {
            size_t off = (((fbase + k) * 4 + nt) * 64 + lane) * 8 + j;
            dst[off] = f2bf(p[k]);
        }
    }
    const float* dsrc[2] = { dw1, dw2 };
    #pragma unroll
    for (int t = 0; t < 2; ++t) {
        const float* p = dsrc[t] + ((size_t)o * 256 + c) * 3;
        unsigned short* dh = wt + (size_t)(4 + 2 * t) * 196608;
        unsigned short* dl = dh + 196608;
        #pragma unroll
        for (int k = 0; k < 3; ++k) {
            size_t off = (((fbase + k) * 4 + nt) * 64 + lane) * 8 + j;
            float v = p[k];
            unsigned short hi = f2bf(v);
            dh[off] = hi;
            dl[off] = f2bf(v - bf2f(hi));
        }
    }
}

// ============================================================
// K1: x' = x + note_pitch @ np_w + np_b  (R8-exact fp32 LDS GEMM)
// ============================================================
__global__ __launch_bounds__(256) void noteproj_kernel(
    const float* __restrict__ x, const float* __restrict__ note,
    const float* __restrict__ w, const float* __restrict__ bias,
    float* __restrict__ xp, unsigned* __restrict__ red)
{
    if (blockIdx.x == 0 && blockIdx.y == 0 && threadIdx.x == 0) {
        red[0] = 0u;            // max ||xn||
        red[1] = 0x7F7FFFFFu;   // min ||x'||  (FLT_MAX bits)
        red[2] = 0u;            // max ||x'||
    }
    __shared__ float As[16][66];
    __shared__ float Bs[16][68];
    const int tid = threadIdx.x;
    const int m0 = blockIdx.x << 6;
    const int o0 = blockIdx.y << 6;
    const int tc = tid & 15, tr = tid >> 4;
    const int r = tr << 2, oc = tc << 2;
    const int tA = tid >> 2, cg = (tid & 3) << 2;
    const int cB = tid >> 4, oB = (tid & 15) << 2;
    float acc[4][4] = {};

    for (int c0 = 0; c0 < D_; c0 += 16) {
        float4 av = *(const float4*)(note + (size_t)(m0 + tA) * D_ + c0 + cg);
        As[cg + 0][tA] = av.x; As[cg + 1][tA] = av.y;
        As[cg + 2][tA] = av.z; As[cg + 3][tA] = av.w;
        *(float4*)&Bs[cB][oB] = *(const float4*)(w + (size_t)(c0 + cB) * D_ + o0 + oB);
        __syncthreads();
        #pragma unroll
        for (int c = 0; c < 16; ++c) {
            float a[4], bv[4];
            #pragma unroll
            for (int m = 0; m < 4; ++m) a[m] = As[c][r + m];
            #pragma unroll
            for (int j = 0; j < 4; ++j) bv[j] = Bs[c][oc + j];
            #pragma unroll
            for (int i = 0; i < 4; ++i)
                #pragma unroll
                for (int j = 0; j < 4; ++j)
                    acc[i][j] = fmaf(a[i], bv[j], acc[i][j]);
        }
        __syncthreads();
    }
    #pragma unroll
    for (int i = 0; i < 4; ++i) {
        size_t row = (size_t)(m0 + r + i);
        const float* xr = x + row * D_ + o0 + oc;
        float4 v;
        v.x = acc[i][0] + bias[o0 + oc + 0] + xr[0];
        v.y = acc[i][1] + bias[o0 + oc + 1] + xr[1];
        v.z = acc[i][2] + bias[o0 + oc + 2] + xr[2];
        v.w = acc[i][3] + bias[o0 + oc + 3] + xr[3];
        *(float4*)(xp + row * D_ + o0 + oc) = v;
    }
}

// ============================================================
// K2: layernorm + norms + bf16 copies. 1 wave = 1 row.
// ============================================================
__global__ __launch_bounds__(256) void rowstats_kernel(
    const float* __restrict__ xp, const float* __restrict__ g, const float* __restrict__ bb,
    unsigned short* __restrict__ xnh, unsigned short* __restrict__ xnl,
    float* __restrict__ nxn, float* __restrict__ nx,
    unsigned short* __restrict__ xpb)
{
    int row = blockIdx.x * 4 + (threadIdx.x >> 6);
    int lane = threadIdx.x & 63;
    float4 v = ((const float4*)(xp + (size_t)row * D_))[lane];
    ushort4 bv4;
    bv4.x = f2bf(v.x); bv4.y = f2bf(v.y); bv4.z = f2bf(v.z); bv4.w = f2bf(v.w);
    ((ushort4*)xpb)[(size_t)row * 64 + lane] = bv4;

    float s = v.x + v.y + v.z + v.w;
    float sq = v.x * v.x + v.y * v.y + v.z * v.z + v.w * v.w;
    #pragma unroll
    for (int m = 32; m; m >>= 1) { s += __shfl_xor(s, m); sq += __shfl_xor(sq, m); }
    float mean = s * (1.f / 256.f);
    float var = sq * (1.f / 256.f) - mean * mean;
    float rs = rsqrtf(var + 1e-5f);
    float4 gv = ((const float4*)g)[lane];
    float4 bv = ((const float4*)bb)[lane];
    float4 o;
    o.x = gv.x * (v.x - mean) * rs + bv.x;
    o.y = gv.y * (v.y - mean) * rs + bv.y;
    o.z = gv.z * (v.z - mean) * rs + bv.z;
    o.w = gv.w * (v.w - mean) * rs + bv.w;
    ushort4 h4, l4;
    h4.x = f2bf(o.x); l4.x = f2bf(o.x - bf2f(h4.x));
    h4.y = f2bf(o.y); l4.y = f2bf(o.y - bf2f(h4.y));
    h4.z = f2bf(o.z); l4.z = f2bf(o.z - bf2f(h4.z));
    h4.w = f2bf(o.w); l4.w = f2bf(o.w - bf2f(h4.w));
    ((ushort4*)xnh)[(size_t)row * 64 + lane] = h4;
    ((ushort4*)xnl)[(size_t)row * 64 + lane] = l4;

    float q = o.x * o.x + o.y * o.y + o.z * o.z + o.w * o.w;
    #pragma unroll
    for (int m = 32; m; m >>= 1) q += __shfl_xor(q, m);
    if (lane == 0) { nxn[row] = sqrtf(q); nx[row] = sqrtf(sq); }
}

// ============================================================
// K3: fast global reduce via uint-monotonic atomics (positive floats)
// ============================================================
__global__ __launch_bounds__(256) void reduce_fast_kernel(
    const float* __restrict__ nxn, const float* __restrict__ nx, unsigned* __restrict__ red)
{
    int tid = threadIdx.x;
    int lane = tid & 63, wave = tid >> 6;
    float mxn = 0.f, mnx = 3.0e38f, mxx = 0.f;
    for (int i = blockIdx.x * 256 + tid; i < ROWS; i += 32 * 256) {
        mxn = fmaxf(mxn, nxn[i]);
        float v = nx[i];
        mnx = fminf(mnx, v);
        mxx = fmaxf(mxx, v);
    }
    #pragma unroll
    for (int m = 32; m; m >>= 1) {
        mxn = fmaxf(mxn, __shfl_xor(mxn, m));
        mnx = fminf(mnx, __shfl_xor(mnx, m));
        mxx = fmaxf(mxx, __shfl_xor(mxx, m));
    }
    __shared__ float a0[4], a1[4], a2[4];
    if (lane == 0) { a0[wave] = mxn; a1[wave] = mnx; a2[wave] = mxx; }
    __syncthreads();
    if (tid == 0) {
        #pragma unroll
        for (int w2 = 1; w2 < 4; ++w2) {
            mxn = fmaxf(mxn, a0[w2]); mnx = fminf(mnx, a1[w2]); mxx = fmaxf(mxx, a2[w2]);
        }
        atomicMax(&red[0], __float_as_uint(mxn));
        atomicMin(&red[1], __float_as_uint(mnx));
        atomicMax(&red[2], __float_as_uint(mxx));
    }
}

// ============================================================
// K4: LDS-free conv stage (R8 structure). Change vs R8:
//   pp/ep epilogue is ALWAYS bf16 (stage2 h2_pp/h2_ep now bf16) —
//   identical code to the proven s1 bf16 path. dp unchanged
//   (s1: hi/lo pair; s2: fp32 — durations keep full precision).
// grid (128, 4, 3), 256 threads.
// ============================================================
struct ConvAll {
    const unsigned short* dp_in_hi; const unsigned short* dp_in_lo;   // [B*S][256]
    const unsigned short* dp_wt_hi; const unsigned short* dp_wt_lo;   // frag-order
    const float* dp_bias;
    unsigned short* dp_out_hi; unsigned short* dp_out_lo;  // stage1 (bfout=1)
    float* dp_out_f;                                        // stage2 (bfout=0)
    const unsigned short* inb[2];
    const unsigned short* wt[2];     // frag-order
    const float* bias[2];
    unsigned short* out[2];          // pp/ep outputs: ALWAYS bf16
    int bfout;                       // dp only: 1=hi/lo pair, 0=fp32
};

__global__ __launch_bounds__(256) void convall_kernel(ConvAll cb)
{
    __shared__ __align__(16) char smem[36864];   // 128 x 72 f32 epilogue buffer
    const int tid = threadIdx.x;
    const int z = blockIdx.z;
    const int o0 = blockIdx.y << 6;
    const int wave = tid >> 6, lane = tid & 63;
    const int lm = lane & 15, lk8 = (lane >> 4) << 3;
    const int q4 = (lane >> 4) << 2;

    if (z == 0) {
        // ---------------- dp split-bf16 path: 256-row tile, 64 rows/wave ----------------
        if (blockIdx.x >= 64) return;           // whole block exits: no barrier hazard
        const int b = blockIdx.x >> 2;
        const int S0 = (blockIdx.x & 3) << 8;   // 0,256,512,768
        const int wr = wave << 6;               // wave's first row (0,64,128,192)
        f32x4 acc[4][4] = {};
        unsigned aoff[4][3]; bool aok[4][3];
        #pragma unroll
        for (int st = 0; st < 4; ++st)
            #pragma unroll
            for (int k = 0; k < 3; ++k) {
                int srow = S0 + wr + (st << 4) + lm + k - 1;
                aok[st][k] = (srow >= 0) && (srow < S_);
                int sr = srow < 0 ? 0 : (srow >= S_ ? S_ - 1 : srow);
                aoff[st][k] = (unsigned)(b * S_ + sr) * D_ + lk8;
            }
        const unsigned short* ih = cb.dp_in_hi;
        const unsigned short* il = cb.dp_in_lo;
        const unsigned short* wh = cb.dp_wt_hi + (size_t)(o0 >> 6) * 49152 + (size_t)lane * 8;
        const unsigned short* wl = cb.dp_wt_lo + (size_t)(o0 >> 6) * 49152 + (size_t)lane * 8;
        for (int c0 = 0; c0 < D_; c0 += 32) {
            const int cbi = c0 >> 5;
            #pragma unroll
            for (int k = 0; k < 3; ++k) {
                uint4 ah4[4], al4[4];
                #pragma unroll
                for (int st = 0; st < 4; ++st) {
                    uint4 vh = make_uint4(0u, 0u, 0u, 0u);
                    uint4 vl = make_uint4(0u, 0u, 0u, 0u);
                    if (aok[st][k]) {
                        unsigned off = aoff[st][k] + c0;
                        vh = *(const uint4*)(const void*)(ih + off);
                        vl = *(const uint4*)(const void*)(il + off);
                    }
                    ah4[st] = vh; al4[st] = vl;
                }
                const unsigned short* bph = wh + (size_t)((cbi * 3 + k) * 4) * 512;
                const unsigned short* bpl = wl + (size_t)((cbi * 3 + k) * 4) * 512;
                #pragma unroll
                for (int nt = 0; nt < 4; ++nt) {
                    short8x bh = *(const short8x*)(const void*)(bph + nt * 512);
                    short8x bl = *(const short8x*)(const void*)(bpl + nt * 512);
                    #pragma unroll
                    for (int st = 0; st < 4; ++st) {
                        short8x ah = *(short8x*)&ah4[st];
                        short8x al = *(short8x*)&al4[st];
                        acc[st][nt] = __builtin_amdgcn_mfma_f32_16x16x32_bf16(ah, bh, acc[st][nt], 0, 0, 0);
                        acc[st][nt] = __builtin_amdgcn_mfma_f32_16x16x32_bf16(ah, bl, acc[st][nt], 0, 0, 0);
                        acc[st][nt] = __builtin_amdgcn_mfma_f32_16x16x32_bf16(al, bh, acc[st][nt], 0, 0, 0);
                    }
                }
            }
        }
        // ---- dp epilogue: 256 rows via two 128-row halves ----
        float bvv[4];
        #pragma unroll
        for (int nt = 0; nt < 4; ++nt) bvv[nt] = cb.dp_bias[o0 + (nt << 4) + lm];
        const int hw = wr >> 7;        // 0 for waves 0,1; 1 for waves 2,3
        const int base = wr & 127;     // 0 or 64 within the half
        if (cb.bfout) {
            unsigned short* L = (unsigned short*)smem;           // [128][72] ushorts
            #pragma unroll
            for (int pass = 0; pass < 2; ++pass) {
                unsigned short* outp = pass ? cb.dp_out_lo : cb.dp_out_hi;
                #pragma unroll
                for (int h = 0; h < 2; ++h) {
                    if (pass | h) __syncthreads();
                    if (hw == h) {
                        #pragma unroll
                        for (int nt = 0; nt < 4; ++nt)
                            #pragma unroll
                            for (int st = 0; st < 4; ++st)
                                #pragma unroll
                                for (int rg = 0; rg < 4; ++rg) {
                                    int lrow = base + (st << 4) + q4 + rg;
                                    int lcol = (nt << 4) + lm;
                                    float v = fmaxf(acc[st][nt][rg] + bvv[nt], 0.f);
                                    unsigned short hi = f2bf(v);
                                    L[lrow * 72 + lcol] = pass ? f2bf(v - bf2f(hi)) : hi;
                                }
                    }
                    __syncthreads();
                    #pragma unroll
                    for (int q = 0; q < 4; ++q) {
                        int flat = (q << 8) + tid;
                        int rrow = flat >> 3, u = flat & 7;
                        uint4 val = *(const uint4*)(const void*)&L[rrow * 72 + (u << 3)];
                        *(uint4*)(void*)(outp + ((size_t)(b * S_ + S0 + (h << 7) + rrow)) * D_ + o0 + (u << 3)) = val;
                    }
                }
            }
        } else {
            float* Lf = (float*)smem;                            // [128][72] floats
            #pragma unroll
            for (int h = 0; h < 2; ++h) {
                if (h) __syncthreads();
                if (hw == h) {
                    #pragma unroll
                    for (int nt = 0; nt < 4; ++nt)
                        #pragma unroll
                        for (int st = 0; st < 4; ++st)
                            #pragma unroll
                            for (int rg = 0; rg < 4; ++rg) {
                                int lrow = base + (st << 4) + q4 + rg;
                                int lcol = (nt << 4) + lm;
                                Lf[lrow * 72 + lcol] = fmaxf(acc[st][nt][rg] + bvv[nt], 0.f);
                            }
                }
                __syncthreads();
                #pragma unroll
                for (int q = 0; q < 8; ++q) {
                    int flat = (q << 8) + tid;
                    int rrow = flat >> 4, u4 = flat & 15;
                    uint4 val = *(const uint4*)(const void*)&Lf[rrow * 72 + (u4 << 2)];
                    *(uint4*)(void*)(cb.dp_out_f + ((size_t)(b * S_ + S0 + (h << 7) + rrow)) * D_ + o0 + (u4 << 2)) = val;
                }
            }
        }
    } else {
        // ---------------- pp/ep path: 256-row tile, 64 rows/wave ----------------
        if (blockIdx.x >= 64) return;           // whole block exits: no barrier hazard
        const int z1 = z - 1;
        const int b = blockIdx.x >> 2;
        const int S0 = (blockIdx.x & 3) << 8;   // 0,256,512,768
        const int wr = wave << 6;               // wave's first row (0,64,128,192)
        f32x4 acc[4][4] = {};
        unsigned aoff[4][3]; bool aok[4][3];
        #pragma unroll
        for (int st = 0; st < 4; ++st)
            #pragma unroll
            for (int k = 0; k < 3; ++k) {
                int srow = S0 + wr + (st << 4) + lm + k - 1;
                aok[st][k] = (srow >= 0) && (srow < S_);
                int sr = srow < 0 ? 0 : (srow >= S_ ? S_ - 1 : srow);
                aoff[st][k] = (unsigned)(b * S_ + sr) * D_ + lk8;
            }
        const unsigned short* inp = cb.inb[z1];
        const unsigned short* wp = cb.wt[z1] + (size_t)(o0 >> 6) * 49152 + (size_t)lane * 8;
        for (int c0 = 0; c0 < D_; c0 += 32) {
            const int cbi = c0 >> 5;
            uint4 pa[4][3];
            #pragma unroll
            for (int st = 0; st < 4; ++st)
                #pragma unroll
                for (int k = 0; k < 3; ++k) {
                    uint4 v = make_uint4(0u, 0u, 0u, 0u);
                    if (aok[st][k]) v = *(const uint4*)(const void*)(inp + aoff[st][k] + c0);
                    pa[st][k] = v;
                }
            #pragma unroll
            for (int k = 0; k < 3; ++k) {
                const unsigned short* bp = wp + (size_t)((cbi * 3 + k) * 4) * 512;
                short8x a0 = *(short8x*)&pa[0][k];
                short8x a1 = *(short8x*)&pa[1][k];
                short8x a2 = *(short8x*)&pa[2][k];
                short8x a3 = *(short8x*)&pa[3][k];
                #pragma unroll
                for (int nt = 0; nt < 4; ++nt) {
                    short8x bf = *(const short8x*)(const void*)(bp + nt * 512);
                    acc[0][nt] = __builtin_amdgcn_mfma_f32_16x16x32_bf16(a0, bf, acc[0][nt], 0, 0, 0);
                    acc[1][nt] = __builtin_amdgcn_mfma_f32_16x16x32_bf16(a1, bf, acc[1][nt], 0, 0, 0);
                    acc[2][nt] = __builtin_amdgcn_mfma_f32_16x16x32_bf16(a2, bf, acc[2][nt], 0, 0, 0);
                    acc[3][nt] = __builtin_amdgcn_mfma_f32_16x16x32_bf16(a3, bf, acc[3][nt], 0, 0, 0);
                }
            }
        }
        // ---- pp/ep epilogue: ALWAYS bf16, two 128-row passes ----
        float bvv[4];
        #pragma unroll
        for (int nt = 0; nt < 4; ++nt) bvv[nt] = cb.bias[z1][o0 + (nt << 4) + lm];
        const int hw = wr >> 7;        // 0 for waves 0,1; 1 for waves 2,3
        const int base = wr & 127;     // 0 or 64 within the half
        unsigned short* L = (unsigned short*)smem;           // [128][72] ushorts
        unsigned short* outp = cb.out[z1];
        #pragma unroll
        for (int h = 0; h < 2; ++h) {
            if (h) __syncthreads();
            if (hw == h) {
                #pragma unroll
                for (int nt = 0; nt < 4; ++nt)
                    #pragma unroll
                    for (int st = 0; st < 4; ++st)
                        #pragma unroll
                        for (int rg = 0; rg < 4; ++rg) {
                            int lrow = base + (st << 4) + q4 + rg;
                            int lcol = (nt << 4) + lm;
                            L[lrow * 72 + lcol] = f2bf(fmaxf(acc[st][nt][rg] + bvv[nt], 0.f));
                        }
            }
            __syncthreads();
            #pragma unroll
            for (int q = 0; q < 4; ++q) {
                int flat = (q << 8) + tid;
                int rrow = flat >> 3, u = flat & 7;
                uint4 val = *(const uint4*)(const void*)&L[rrow * 72 + (u << 3)];
                *(uint4*)(void*)(outp + ((size_t)(b * S_ + S0 + (h << 7) + rrow)) * D_ + o0 + (u << 3)) = val;
            }
        }
    }
}

// ============================================================
// K5: fused final linears + epilogues. 1 wave = 1 row.
// h2pp/h2ep are now bf16 (8B/lane loads); h2dp stays fp32.
// ============================================================
__global__ __launch_bounds__(256) void linfused_kernel(
    const float* __restrict__ h2dp,
    const unsigned short* __restrict__ h2pp, const unsigned short* __restrict__ h2ep,
    const float* __restrict__ dp_wl, const float* __restrict__ dp_bl,
    const float* __restrict__ pp_wl, const float* __restrict__ pp_bl,
    const float* __restrict__ ep_wl, const float* __restrict__ ep_bl,
    const float* __restrict__ nxn, const float* __restrict__ nx, const unsigned* __restrict__ red,
    float* __restrict__ o_logdur, float* __restrict__ o_dur, float* __restrict__ durf,
    float* __restrict__ o_pitch, float* __restrict__ o_energy)
{
    int row = blockIdx.x * 4 + (threadIdx.x >> 6);
    int lane = threadIdx.x & 63;
    float4 hd = ((const float4*)(h2dp + (size_t)row * F_))[lane];
    float4 wd = ((const float4*)dp_wl)[lane];
    float ad = hd.x * wd.x + hd.y * wd.y + hd.z * wd.z + hd.w * wd.w;

    ushort4 heu = ((const ushort4*)h2ep)[(size_t)row * 64 + lane];
    float4 we = ((const float4*)ep_wl)[lane];
    float ae = bf2f(heu.x) * we.x + bf2f(heu.y) * we.y + bf2f(heu.z) * we.z + bf2f(heu.w) * we.w;

    ushort4 hpu = ((const ushort4*)h2pp)[(size_t)row * 64 + lane];
    float hv[4] = { bf2f(hpu.x), bf2f(hpu.y), bf2f(hpu.z), bf2f(hpu.w) };
    float a0 = 0.f, a1 = 0.f, a2 = 0.f;
    #pragma unroll
    for (int u = 0; u < 4; ++u) {
        int c = lane * 4 + u;
        a0 = fmaf(hv[u], pp_wl[c * 3 + 0], a0);
        a1 = fmaf(hv[u], pp_wl[c * 3 + 1], a1);
        a2 = fmaf(hv[u], pp_wl[c * 3 + 2], a2);
    }
    #pragma unroll
    for (int m = 32; m; m >>= 1) {
        ad += __shfl_xor(ad, m);
        ae += __shfl_xor(ae, m);
        a0 += __shfl_xor(a0, m); a1 += __shfl_xor(a1, m); a2 += __shfl_xor(a2, m);
    }
    if (lane == 0) {
        float base = ad + dp_bl[0];
        float es = 0.8f + 0.4f * (nxn[row] / __uint_as_float(red[0]));
        int s = row & (S_ - 1);
        float ps = 1.0f + 0.1f * ((float)s * (1.f / (float)S_));
        float ld = base * es * ps;
        float d = expf(ld);
        o_logdur[row] = ld;
        o_dur[row] = d;
        durf[row] = d;
        float p0 = a0 + pp_bl[0], p1 = a1 + pp_bl[1], p2 = a2 + pp_bl[2];
        float mn = __uint_as_float(red[1]), mx = __uint_as_float(red[2]);
        float en = (nx[row] - mn) / (mx - mn + 1e-8f);
        float f0s = 100.f + 400.f * en;
        float f0b = expf(p0) * f0s * (1.f / 220.f);
        o_pitch[(size_t)row * 3 + 0] = logf(f0b + 1e-8f);
        o_pitch[(size_t)row * 3 + 1] = p1;
        o_pitch[(size_t)row * 3 + 2] = p2;
        o_energy[row] = ae + ep_bl[0];
    }
}

// ============================================================
// K6: per-batch round->cumsum->clip->searchsorted + mel mask
// ============================================================
__global__ __launch_bounds__(1024) void regulate_kernel(
    const float* __restrict__ durf, int* __restrict__ idxbuf, float* __restrict__ mask)
{
    __shared__ int cum[S_];
    int b = blockIdx.x;
    int t = threadIdx.x;
    int d = (int)rintf(durf[b * S_ + t]);
    cum[t] = d;
    __syncthreads();
    for (int off = 1; off < S_; off <<= 1) {
        int v = (t >= off) ? cum[t - off] : 0;
        __syncthreads();
        cum[t] += v;
        __syncthreads();
    }
    cum[t] = min(cum[t], T_);
    __syncthreads();
    int total = cum[S_ - 1];
    for (int t0 = t; t0 < T_; t0 += S_) {
        int lo = 0, hi = S_;
        while (lo < hi) {
            int mid = (lo + hi) >> 1;
            if (cum[mid] <= t0) lo = mid + 1; else hi = mid;
        }
        int id = min(lo, S_ - 1);
        bool masked = (t0 >= total);
        idxbuf[b * T_ + t0] = masked ? -1 : id;
        mask[(size_t)b * T_ + t0] = masked ? 1.f : 0.f;
    }
}

// ============================================================
// K7: expanded gather. 1 wave = 1 (b,t) row, float4/lane
// ============================================================
__global__ __launch_bounds__(256) void expand_kernel(
    const float* __restrict__ xp, const int* __restrict__ idxbuf, float* __restrict__ expd)
{
    int row = blockIdx.x * 4 + (threadIdx.x >> 6);
    int lane = threadIdx.x & 63;
    int id = idxbuf[row];
    int b = row >> 13;
    float4 v = make_float4(0.f, 0.f, 0.f, 0.f);
    if (id >= 0)
        v = ((const float4*)(xp + ((size_t)(b * S_ + id)) * D_))[lane];
    ((float4*)(expd + (size_t)row * D_))[lane] = v;
}

// ============================================================
extern "C" void kernel_launch(void* const* d_in, const int* in_sizes, int n_in,
                              void* d_out, int out_size, void* d_ws, size_t ws_size,
                              hipStream_t stream) {
    const float* x     = (const float*)d_in[0];
    const float* note  = (const float*)d_in[2];
    const float* ln_g  = (const float*)d_in[3];
    const float* ln_b  = (const float*)d_in[4];
    const float* dp_w1 = (const float*)d_in[5];
    const float* dp_b1 = (const float*)d_in[6];
    const float* dp_w2 = (const float*)d_in[7];
    const float* dp_b2 = (const float*)d_in[8];
    const float* dp_wl = (const float*)d_in[9];
    const float* dp_bl = (const float*)d_in[10];
    const float* pp_w1 = (const float*)d_in[11];
    const float* pp_b1 = (const float*)d_in[12];
    const float* pp_w2 = (const float*)d_in[13];
    const float* pp_b2 = (const float*)d_in[14];
    const float* pp_wl = (const float*)d_in[15];
    const float* pp_bl = (const float*)d_in[16];
    const float* ep_w1 = (const float*)d_in[17];
    const float* ep_b1 = (const float*)d_in[18];
    const float* ep_w2 = (const float*)d_in[19];
    const float* ep_b2 = (const float*)d_in[20];
    const float* ep_wl = (const float*)d_in[21];
    const float* ep_bl = (const float*)d_in[22];
    const float* np_w  = (const float*)d_in[23];
    const float* np_b  = (const float*)d_in[24];

    // d_out: logdur | dur | pitch | energy | expanded | melmask
    float* o_logdur = (float*)d_out;
    float* o_dur    = o_logdur + ROWS;
    float* o_pitch  = o_dur + ROWS;
    float* o_energy = o_pitch + ROWS * 3;
    float* o_exp    = o_energy + ROWS;
    float* o_mask   = o_exp + (size_t)B_ * T_ * D_;

    // intermediates inside the expanded region (rewritten last by expand)
    const size_t CH = (size_t)ROWS * D_;      // 4,194,304 floats
    float* h2_dp = o_exp + 0 * CH;
    unsigned short* h2_ppb  = (unsigned short*)(o_exp + 1 * CH);            // CH bf16
    unsigned short* h2_epb  = (unsigned short*)(o_exp + 1 * CH + CH / 2);   // CH bf16
    unsigned short* h1_ppb  = (unsigned short*)(o_exp + 2 * CH);            // CH bf16
    unsigned short* h1_epb  = (unsigned short*)(o_exp + 2 * CH + CH / 2);   // CH bf16
    unsigned short* xp_bf   = (unsigned short*)(o_exp + 3 * CH);            // CH bf16
    unsigned short* xn_hi   = (unsigned short*)(o_exp + 3 * CH + CH / 2);   // CH bf16
    unsigned short* xn_lo   = (unsigned short*)(o_exp + 4 * CH);            // CH bf16
    unsigned short* h1dp_hi = (unsigned short*)(o_exp + 4 * CH + CH / 2);   // CH bf16
    unsigned short* h1dp_lo = (unsigned short*)(o_exp + 5 * CH);            // CH bf16
    unsigned short* wt      = (unsigned short*)(o_exp + 5 * CH + CH / 2);   // 8*196608 bf16
    unsigned short* wt_pp1  = wt;
    unsigned short* wt_ep1  = wt + 196608;
    unsigned short* wt_pp2  = wt + 2 * 196608;
    unsigned short* wt_ep2  = wt + 3 * 196608;
    unsigned short* wt_dp1h = wt + 4 * 196608;
    unsigned short* wt_dp1l = wt + 5 * 196608;
    unsigned short* wt_dp2h = wt + 6 * 196608;
    unsigned short* wt_dp2l = wt + 7 * 196608;

    // d_ws: xprime | norm_xn | norm_x | red | durf | idxbuf
    float* ws_f    = (float*)d_ws;
    float* xprime  = ws_f;
    float* norm_xn = ws_f + CH;
    float* norm_x  = norm_xn + ROWS;
    unsigned* red  = (unsigned*)(norm_x + ROWS);
    float* durf    = (float*)(red + 4);
    int*   idxbuf  = (int*)(durf + ROWS);

    wprep_kernel<<<256, 256, 0, stream>>>(pp_w1, ep_w1, pp_w2, ep_w2, dp_w1, dp_w2, wt);
    noteproj_kernel<<<dim3(ROWS / 64, D_ / 64), 256, 0, stream>>>(x, note, np_w, np_b, xprime, red);
    rowstats_kernel<<<ROWS / 4, 256, 0, stream>>>(xprime, ln_g, ln_b, xn_hi, xn_lo, norm_xn, norm_x, xp_bf);
    reduce_fast_kernel<<<32, 256, 0, stream>>>(norm_xn, norm_x, red);

    dim3 cgrid(B_ * (S_ / 128), F_ / 64, 3);
    ConvAll s1;
    s1.dp_in_hi = xn_hi;   s1.dp_in_lo = xn_lo;
    s1.dp_wt_hi = wt_dp1h; s1.dp_wt_lo = wt_dp1l;
    s1.dp_bias = dp_b1;
    s1.dp_out_hi = h1dp_hi; s1.dp_out_lo = h1dp_lo; s1.dp_out_f = nullptr;
    s1.inb[0] = xp_bf;  s1.wt[0] = wt_pp1; s1.bias[0] = pp_b1; s1.out[0] = h1_ppb;
    s1.inb[1] = xp_bf;  s1.wt[1] = wt_ep1; s1.bias[1] = ep_b1; s1.out[1] = h1_epb;
    s1.bfout = 1;
    convall_kernel<<<cgrid, 256, 0, stream>>>(s1);

    ConvAll s2;
    s2.dp_in_hi = h1dp_hi; s2.dp_in_lo = h1dp_lo;
    s2.dp_wt_hi = wt_dp2h; s2.dp_wt_lo = wt_dp2l;
    s2.dp_bias = dp_b2;
    s2.dp_out_hi = nullptr; s2.dp_out_lo = nullptr; s2.dp_out_f = h2_dp;
    s2.inb[0] = h1_ppb; s2.wt[0] = wt_pp2; s2.bias[0] = pp_b2; s2.out[0] = h2_ppb;
    s2.inb[1] = h1_epb; s2.wt[1] = wt_ep2; s2.bias[1] = ep_b2; s2.out[1] = h2_epb;
    s2.bfout = 0;
    convall_kernel<<<cgrid, 256, 0, stream>>>(s2);

    linfused_kernel<<<ROWS / 4, 256, 0, stream>>>(h2_dp, h2_ppb, h2_epb,
        dp_wl, dp_bl, pp_wl, pp_bl, ep_wl, ep_bl,
        norm_xn, norm_x, red, o_logdur, o_dur, durf, o_pitch, o_energy);

    regulate_kernel<<<B_, 1024, 0, stream>>>(durf, idxbuf, o_mask);
    expand_kernel<<<(B_ * T_) / 4, 256, 0, stream>>>(xprime, idxbuf, o_exp);
}

// Round 11
// 396.637 us; speedup vs baseline: 1.0324x; 1.0201x over previous
//
#include <hip/hip_runtime.h>
#include <math.h>

#define B_ 16
#define S_ 1024
#define D_ 256
#define F_ 256
#define T_ 8192
#define ROWS (B_ * S_)  // 16384

typedef __attribute__((ext_vector_type(8))) short short8x;
typedef __attribute__((ext_vector_type(4))) float f32x4;

static __device__ __forceinline__ unsigned short f2bf(float f) {
    unsigned u = __float_as_uint(f);
    unsigned r = (u + 0x7FFFu + ((u >> 16) & 1u)) >> 16;  // round-to-nearest-even
    return (unsigned short)r;
}
static __device__ __forceinline__ float bf2f(unsigned short h) {
    return __uint_as_float(((unsigned)h) << 16);
}

// ============================================================
// K0: weight prep -> FRAGMENT-ORDER layout (R8-exact).
// Tensors: t0..3 = pp1,ep1,pp2,ep2 (plain bf16); t4..7 = dp1h,dp1l,dp2h,dp2l
// ============================================================
__global__ __launch_bounds__(256) void wprep_kernel(
    const float* __restrict__ pw1, const float* __restrict__ ew1,
    const float* __restrict__ pw2, const float* __restrict__ ew2,
    const float* __restrict__ dw1, const float* __restrict__ dw2,
    unsigned short* __restrict__ wt)
{
    int idx = blockIdx.x * 256 + threadIdx.x;   // 0..65535 -> (o, c)
    int o = idx >> 8, c = idx & 255;
    int o_t = o >> 6, nt = (o >> 4) & 3, lr = o & 15;
    int cbk = c >> 5, hs = (c >> 3) & 3, j = c & 7;
    int lane = hs * 16 + lr;
    size_t fbase = ((size_t)o_t * 8 + cbk) * 3;   // *k later

    const float* srcs[4] = { pw1, ew1, pw2, ew2 };
    #pragma unroll
    for (int t = 0; t < 4; ++t) {
        const float* p = srcs[t] + ((size_t)o * 256 + c) * 3;
        unsigned short* dst = wt + (size_t)t * 196608;
        #pragma unroll
        for (int k = 0; k < 3; ++k) {
            size_t off = (((fbase + k) * 4 + nt) * 64 + lane) * 8 + j;
            dst[off] = f2bf(p[k]);
        }
    }
    const float* dsrc[2] = { dw1, dw2 };
    #pragma unroll
    for (int t = 0; t < 2; ++t) {
        const float* p = dsrc[t] + ((size_t)o * 256 + c) * 3;
        unsigned short* dh = wt + (size_t)(4 + 2 * t) * 196608;
        unsigned short* dl = dh + 196608;
        #pragma unroll
        for (int k = 0; k < 3; ++k) {
            size_t off = (((fbase + k) * 4 + nt) * 64 + lane) * 8 + j;
            float v = p[k];
            unsigned short hi = f2bf(v);
            dh[off] = hi;
            dl[off] = f2bf(v - bf2f(hi));
        }
    }
}

// ============================================================
// K1: x' = x + note_pitch @ np_w + np_b  (R8-exact fp32 LDS GEMM)
// ============================================================
__global__ __launch_bounds__(256) void noteproj_kernel(
    const float* __restrict__ x, const float* __restrict__ note,
    const float* __restrict__ w, const float* __restrict__ bias,
    float* __restrict__ xp, unsigned* __restrict__ red)
{
    if (blockIdx.x == 0 && blockIdx.y == 0 && threadIdx.x == 0) {
        red[0] = 0u;            // max ||xn||
        red[1] = 0x7F7FFFFFu;   // min ||x'||  (FLT_MAX bits)
        red[2] = 0u;            // max ||x'||
    }
    __shared__ float As[16][66];
    __shared__ float Bs[16][68];
    const int tid = threadIdx.x;
    const int m0 = blockIdx.x << 6;
    const int o0 = blockIdx.y << 6;
    const int tc = tid & 15, tr = tid >> 4;
    const int r = tr << 2, oc = tc << 2;
    const int tA = tid >> 2, cg = (tid & 3) << 2;
    const int cB = tid >> 4, oB = (tid & 15) << 2;
    float acc[4][4] = {};

    for (int c0 = 0; c0 < D_; c0 += 16) {
        float4 av = *(const float4*)(note + (size_t)(m0 + tA) * D_ + c0 + cg);
        As[cg + 0][tA] = av.x; As[cg + 1][tA] = av.y;
        As[cg + 2][tA] = av.z; As[cg + 3][tA] = av.w;
        *(float4*)&Bs[cB][oB] = *(const float4*)(w + (size_t)(c0 + cB) * D_ + o0 + oB);
        __syncthreads();
        #pragma unroll
        for (int c = 0; c < 16; ++c) {
            float a[4], bv[4];
            #pragma unroll
            for (int m = 0; m < 4; ++m) a[m] = As[c][r + m];
            #pragma unroll
            for (int j = 0; j < 4; ++j) bv[j] = Bs[c][oc + j];
            #pragma unroll
            for (int i = 0; i < 4; ++i)
                #pragma unroll
                for (int j = 0; j < 4; ++j)
                    acc[i][j] = fmaf(a[i], bv[j], acc[i][j]);
        }
        __syncthreads();
    }
    #pragma unroll
    for (int i = 0; i < 4; ++i) {
        size_t row = (size_t)(m0 + r + i);
        const float* xr = x + row * D_ + o0 + oc;
        float4 v;
        v.x = acc[i][0] + bias[o0 + oc + 0] + xr[0];
        v.y = acc[i][1] + bias[o0 + oc + 1] + xr[1];
        v.z = acc[i][2] + bias[o0 + oc + 2] + xr[2];
        v.w = acc[i][3] + bias[o0 + oc + 3] + xr[3];
        *(float4*)(xp + row * D_ + o0 + oc) = v;
    }
}

// ============================================================
// K2: layernorm + norms + bf16 copies. 1 wave = 1 row.
// ============================================================
__global__ __launch_bounds__(256) void rowstats_kernel(
    const float* __restrict__ xp, const float* __restrict__ g, const float* __restrict__ bb,
    unsigned short* __restrict__ xnh, unsigned short* __restrict__ xnl,
    float* __restrict__ nxn, float* __restrict__ nx,
    unsigned short* __restrict__ xpb)
{
    int row = blockIdx.x * 4 + (threadIdx.x >> 6);
    int lane = threadIdx.x & 63;
    float4 v = ((const float4*)(xp + (size_t)row * D_))[lane];
    ushort4 bv4;
    bv4.x = f2bf(v.x); bv4.y = f2bf(v.y); bv4.z = f2bf(v.z); bv4.w = f2bf(v.w);
    ((ushort4*)xpb)[(size_t)row * 64 + lane] = bv4;

    float s = v.x + v.y + v.z + v.w;
    float sq = v.x * v.x + v.y * v.y + v.z * v.z + v.w * v.w;
    #pragma unroll
    for (int m = 32; m; m >>= 1) { s += __shfl_xor(s, m); sq += __shfl_xor(sq, m); }
    float mean = s * (1.f / 256.f);
    float var = sq * (1.f / 256.f) - mean * mean;
    float rs = rsqrtf(var + 1e-5f);
    float4 gv = ((const float4*)g)[lane];
    float4 bv = ((const float4*)bb)[lane];
    float4 o;
    o.x = gv.x * (v.x - mean) * rs + bv.x;
    o.y = gv.y * (v.y - mean) * rs + bv.y;
    o.z = gv.z * (v.z - mean) * rs + bv.z;
    o.w = gv.w * (v.w - mean) * rs + bv.w;
    ushort4 h4, l4;
    h4.x = f2bf(o.x); l4.x = f2bf(o.x - bf2f(h4.x));
    h4.y = f2bf(o.y); l4.y = f2bf(o.y - bf2f(h4.y));
    h4.z = f2bf(o.z); l4.z = f2bf(o.z - bf2f(h4.z));
    h4.w = f2bf(o.w); l4.w = f2bf(o.w - bf2f(h4.w));
    ((ushort4*)xnh)[(size_t)row * 64 + lane] = h4;
    ((ushort4*)xnl)[(size_t)row * 64 + lane] = l4;

    float q = o.x * o.x + o.y * o.y + o.z * o.z + o.w * o.w;
    #pragma unroll
    for (int m = 32; m; m >>= 1) q += __shfl_xor(q, m);
    if (lane == 0) { nxn[row] = sqrtf(q); nx[row] = sqrtf(sq); }
}

// ============================================================
// K3: fast global reduce via uint-monotonic atomics (positive floats)
// ============================================================
__global__ __launch_bounds__(256) void reduce_fast_kernel(
    const float* __restrict__ nxn, const float* __restrict__ nx, unsigned* __restrict__ red)
{
    int tid = threadIdx.x;
    int lane = tid & 63, wave = tid >> 6;
    float mxn = 0.f, mnx = 3.0e38f, mxx = 0.f;
    for (int i = blockIdx.x * 256 + tid; i < ROWS; i += 32 * 256) {
        mxn = fmaxf(mxn, nxn[i]);
        float v = nx[i];
        mnx = fminf(mnx, v);
        mxx = fmaxf(mxx, v);
    }
    #pragma unroll
    for (int m = 32; m; m >>= 1) {
        mxn = fmaxf(mxn, __shfl_xor(mxn, m));
        mnx = fminf(mnx, __shfl_xor(mnx, m));
        mxx = fmaxf(mxx, __shfl_xor(mxx, m));
    }
    __shared__ float a0[4], a1[4], a2[4];
    if (lane == 0) { a0[wave] = mxn; a1[wave] = mnx; a2[wave] = mxx; }
    __syncthreads();
    if (tid == 0) {
        #pragma unroll
        for (int w2 = 1; w2 < 4; ++w2) {
            mxn = fmaxf(mxn, a0[w2]); mnx = fminf(mnx, a1[w2]); mxx = fmaxf(mxx, a2[w2]);
        }
        atomicMax(&red[0], __float_as_uint(mxn));
        atomicMin(&red[1], __float_as_uint(mnx));
        atomicMax(&red[2], __float_as_uint(mxx));
    }
}

// ============================================================
// K4: LDS-free conv stage (R10 structure). Change vs R10:
//   grid is (64,4,3) — ALL blocks real, no dud-gating. 768 blocks
//   = 3/CU, all resident at t=0 (LDS 36.9KB -> 4/CU ceiling),
//   mixed z-types co-scheduled from the start.
// ============================================================
struct ConvAll {
    const unsigned short* dp_in_hi; const unsigned short* dp_in_lo;   // [B*S][256]
    const unsigned short* dp_wt_hi; const unsigned short* dp_wt_lo;   // frag-order
    const float* dp_bias;
    unsigned short* dp_out_hi; unsigned short* dp_out_lo;  // stage1 (bfout=1)
    float* dp_out_f;                                        // stage2 (bfout=0)
    const unsigned short* inb[2];
    const unsigned short* wt[2];     // frag-order
    const float* bias[2];
    unsigned short* out[2];          // pp/ep outputs: ALWAYS bf16
    int bfout;                       // dp only: 1=hi/lo pair, 0=fp32
};

__global__ __launch_bounds__(256) void convall_kernel(ConvAll cb)
{
    __shared__ __align__(16) char smem[36864];   // 128 x 72 f32 epilogue buffer
    const int tid = threadIdx.x;
    const int z = blockIdx.z;
    const int o0 = blockIdx.y << 6;
    const int wave = tid >> 6, lane = tid & 63;
    const int lm = lane & 15, lk8 = (lane >> 4) << 3;
    const int q4 = (lane >> 4) << 2;

    if (z == 0) {
        // ---------------- dp split-bf16 path: 256-row tile, 64 rows/wave ----------------
        const int b = blockIdx.x >> 2;
        const int S0 = (blockIdx.x & 3) << 8;   // 0,256,512,768
        const int wr = wave << 6;               // wave's first row (0,64,128,192)
        f32x4 acc[4][4] = {};
        unsigned aoff[4][3]; bool aok[4][3];
        #pragma unroll
        for (int st = 0; st < 4; ++st)
            #pragma unroll
            for (int k = 0; k < 3; ++k) {
                int srow = S0 + wr + (st << 4) + lm + k - 1;
                aok[st][k] = (srow >= 0) && (srow < S_);
                int sr = srow < 0 ? 0 : (srow >= S_ ? S_ - 1 : srow);
                aoff[st][k] = (unsigned)(b * S_ + sr) * D_ + lk8;
            }
        const unsigned short* ih = cb.dp_in_hi;
        const unsigned short* il = cb.dp_in_lo;
        const unsigned short* wh = cb.dp_wt_hi + (size_t)(o0 >> 6) * 49152 + (size_t)lane * 8;
        const unsigned short* wl = cb.dp_wt_lo + (size_t)(o0 >> 6) * 49152 + (size_t)lane * 8;
        for (int c0 = 0; c0 < D_; c0 += 32) {
            const int cbi = c0 >> 5;
            #pragma unroll
            for (int k = 0; k < 3; ++k) {
                uint4 ah4[4], al4[4];
                #pragma unroll
                for (int st = 0; st < 4; ++st) {
                    uint4 vh = make_uint4(0u, 0u, 0u, 0u);
                    uint4 vl = make_uint4(0u, 0u, 0u, 0u);
                    if (aok[st][k]) {
                        unsigned off = aoff[st][k] + c0;
                        vh = *(const uint4*)(const void*)(ih + off);
                        vl = *(const uint4*)(const void*)(il + off);
                    }
                    ah4[st] = vh; al4[st] = vl;
                }
                const unsigned short* bph = wh + (size_t)((cbi * 3 + k) * 4) * 512;
                const unsigned short* bpl = wl + (size_t)((cbi * 3 + k) * 4) * 512;
                #pragma unroll
                for (int nt = 0; nt < 4; ++nt) {
                    short8x bh = *(const short8x*)(const void*)(bph + nt * 512);
                    short8x bl = *(const short8x*)(const void*)(bpl + nt * 512);
                    #pragma unroll
                    for (int st = 0; st < 4; ++st) {
                        short8x ah = *(short8x*)&ah4[st];
                        short8x al = *(short8x*)&al4[st];
                        acc[st][nt] = __builtin_amdgcn_mfma_f32_16x16x32_bf16(ah, bh, acc[st][nt], 0, 0, 0);
                        acc[st][nt] = __builtin_amdgcn_mfma_f32_16x16x32_bf16(ah, bl, acc[st][nt], 0, 0, 0);
                        acc[st][nt] = __builtin_amdgcn_mfma_f32_16x16x32_bf16(al, bh, acc[st][nt], 0, 0, 0);
                    }
                }
            }
        }
        // ---- dp epilogue: 256 rows via two 128-row halves ----
        float bvv[4];
        #pragma unroll
        for (int nt = 0; nt < 4; ++nt) bvv[nt] = cb.dp_bias[o0 + (nt << 4) + lm];
        const int hw = wr >> 7;        // 0 for waves 0,1; 1 for waves 2,3
        const int base = wr & 127;     // 0 or 64 within the half
        if (cb.bfout) {
            unsigned short* L = (unsigned short*)smem;           // [128][72] ushorts
            #pragma unroll
            for (int pass = 0; pass < 2; ++pass) {
                unsigned short* outp = pass ? cb.dp_out_lo : cb.dp_out_hi;
                #pragma unroll
                for (int h = 0; h < 2; ++h) {
                    if (pass | h) __syncthreads();
                    if (hw == h) {
                        #pragma unroll
                        for (int nt = 0; nt < 4; ++nt)
                            #pragma unroll
                            for (int st = 0; st < 4; ++st)
                                #pragma unroll
                                for (int rg = 0; rg < 4; ++rg) {
                                    int lrow = base + (st << 4) + q4 + rg;
                                    int lcol = (nt << 4) + lm;
                                    float v = fmaxf(acc[st][nt][rg] + bvv[nt], 0.f);
                                    unsigned short hi = f2bf(v);
                                    L[lrow * 72 + lcol] = pass ? f2bf(v - bf2f(hi)) : hi;
                                }
                    }
                    __syncthreads();
                    #pragma unroll
                    for (int q = 0; q < 4; ++q) {
                        int flat = (q << 8) + tid;
                        int rrow = flat >> 3, u = flat & 7;
                        uint4 val = *(const uint4*)(const void*)&L[rrow * 72 + (u << 3)];
                        *(uint4*)(void*)(outp + ((size_t)(b * S_ + S0 + (h << 7) + rrow)) * D_ + o0 + (u << 3)) = val;
                    }
                }
            }
        } else {
            float* Lf = (float*)smem;                            // [128][72] floats
            #pragma unroll
            for (int h = 0; h < 2; ++h) {
                if (h) __syncthreads();
                if (hw == h) {
                    #pragma unroll
                    for (int nt = 0; nt < 4; ++nt)
                        #pragma unroll
                        for (int st = 0; st < 4; ++st)
                            #pragma unroll
                            for (int rg = 0; rg < 4; ++rg) {
                                int lrow = base + (st << 4) + q4 + rg;
                                int lcol = (nt << 4) + lm;
                                Lf[lrow * 72 + lcol] = fmaxf(acc[st][nt][rg] + bvv[nt], 0.f);
                            }
                }
                __syncthreads();
                #pragma unroll
                for (int q = 0; q < 8; ++q) {
                    int flat = (q << 8) + tid;
                    int rrow = flat >> 4, u4 = flat & 15;
                    uint4 val = *(const uint4*)(const void*)&Lf[rrow * 72 + (u4 << 2)];
                    *(uint4*)(void*)(cb.dp_out_f + ((size_t)(b * S_ + S0 + (h << 7) + rrow)) * D_ + o0 + (u4 << 2)) = val;
                }
            }
        }
    } else {
        // ---------------- pp/ep path: 256-row tile, 64 rows/wave ----------------
        const int z1 = z - 1;
        const int b = blockIdx.x >> 2;
        const int S0 = (blockIdx.x & 3) << 8;   // 0,256,512,768
        const int wr = wave << 6;               // wave's first row (0,64,128,192)
        f32x4 acc[4][4] = {};
        unsigned aoff[4][3]; bool aok[4][3];
        #pragma unroll
        for (int st = 0; st < 4; ++st)
            #pragma unroll
            for (int k = 0; k < 3; ++k) {
                int srow = S0 + wr + (st << 4) + lm + k - 1;
                aok[st][k] = (srow >= 0) && (srow < S_);
                int sr = srow < 0 ? 0 : (srow >= S_ ? S_ - 1 : srow);
                aoff[st][k] = (unsigned)(b * S_ + sr) * D_ + lk8;
            }
        const unsigned short* inp = cb.inb[z1];
        const unsigned short* wp = cb.wt[z1] + (size_t)(o0 >> 6) * 49152 + (size_t)lane * 8;
        for (int c0 = 0; c0 < D_; c0 += 32) {
            const int cbi = c0 >> 5;
            uint4 pa[4][3];
            #pragma unroll
            for (int st = 0; st < 4; ++st)
                #pragma unroll
                for (int k = 0; k < 3; ++k) {
                    uint4 v = make_uint4(0u, 0u, 0u, 0u);
                    if (aok[st][k]) v = *(const uint4*)(const void*)(inp + aoff[st][k] + c0);
                    pa[st][k] = v;
                }
            #pragma unroll
            for (int k = 0; k < 3; ++k) {
                const unsigned short* bp = wp + (size_t)((cbi * 3 + k) * 4) * 512;
                short8x a0 = *(short8x*)&pa[0][k];
                short8x a1 = *(short8x*)&pa[1][k];
                short8x a2 = *(short8x*)&pa[2][k];
                short8x a3 = *(short8x*)&pa[3][k];
                #pragma unroll
                for (int nt = 0; nt < 4; ++nt) {
                    short8x bf = *(const short8x*)(const void*)(bp + nt * 512);
                    acc[0][nt] = __builtin_amdgcn_mfma_f32_16x16x32_bf16(a0, bf, acc[0][nt], 0, 0, 0);
                    acc[1][nt] = __builtin_amdgcn_mfma_f32_16x16x32_bf16(a1, bf, acc[1][nt], 0, 0, 0);
                    acc[2][nt] = __builtin_amdgcn_mfma_f32_16x16x32_bf16(a2, bf, acc[2][nt], 0, 0, 0);
                    acc[3][nt] = __builtin_amdgcn_mfma_f32_16x16x32_bf16(a3, bf, acc[3][nt], 0, 0, 0);
                }
            }
        }
        // ---- pp/ep epilogue: ALWAYS bf16, two 128-row passes ----
        float bvv[4];
        #pragma unroll
        for (int nt = 0; nt < 4; ++nt) bvv[nt] = cb.bias[z1][o0 + (nt << 4) + lm];
        const int hw = wr >> 7;        // 0 for waves 0,1; 1 for waves 2,3
        const int base = wr & 127;     // 0 or 64 within the half
        unsigned short* L = (unsigned short*)smem;           // [128][72] ushorts
        unsigned short* outp = cb.out[z1];
        #pragma unroll
        for (int h = 0; h < 2; ++h) {
            if (h) __syncthreads();
            if (hw == h) {
                #pragma unroll
                for (int nt = 0; nt < 4; ++nt)
                    #pragma unroll
                    for (int st = 0; st < 4; ++st)
                        #pragma unroll
                        for (int rg = 0; rg < 4; ++rg) {
                            int lrow = base + (st << 4) + q4 + rg;
                            int lcol = (nt << 4) + lm;
                            L[lrow * 72 + lcol] = f2bf(fmaxf(acc[st][nt][rg] + bvv[nt], 0.f));
                        }
            }
            __syncthreads();
            #pragma unroll
            for (int q = 0; q < 4; ++q) {
                int flat = (q << 8) + tid;
                int rrow = flat >> 3, u = flat & 7;
                uint4 val = *(const uint4*)(const void*)&L[rrow * 72 + (u << 3)];
                *(uint4*)(void*)(outp + ((size_t)(b * S_ + S0 + (h << 7) + rrow)) * D_ + o0 + (u << 3)) = val;
            }
        }
    }
}

// ============================================================
// K5: fused final linears + epilogues. 1 wave = 1 row.
// h2pp/h2ep are bf16 (8B/lane loads); h2dp stays fp32.
// ============================================================
__global__ __launch_bounds__(256) void linfused_kernel(
    const float* __restrict__ h2dp,
    const unsigned short* __restrict__ h2pp, const unsigned short* __restrict__ h2ep,
    const float* __restrict__ dp_wl, const float* __restrict__ dp_bl,
    const float* __restrict__ pp_wl, const float* __restrict__ pp_bl,
    const float* __restrict__ ep_wl, const float* __restrict__ ep_bl,
    const float* __restrict__ nxn, const float* __restrict__ nx, const unsigned* __restrict__ red,
    float* __restrict__ o_logdur, float* __restrict__ o_dur, float* __restrict__ durf,
    float* __restrict__ o_pitch, float* __restrict__ o_energy)
{
    int row = blockIdx.x * 4 + (threadIdx.x >> 6);
    int lane = threadIdx.x & 63;
    float4 hd = ((const float4*)(h2dp + (size_t)row * F_))[lane];
    float4 wd = ((const float4*)dp_wl)[lane];
    float ad = hd.x * wd.x + hd.y * wd.y + hd.z * wd.z + hd.w * wd.w;

    ushort4 heu = ((const ushort4*)h2ep)[(size_t)row * 64 + lane];
    float4 we = ((const float4*)ep_wl)[lane];
    float ae = bf2f(heu.x) * we.x + bf2f(heu.y) * we.y + bf2f(heu.z) * we.z + bf2f(heu.w) * we.w;

    ushort4 hpu = ((const ushort4*)h2pp)[(size_t)row * 64 + lane];
    float hv[4] = { bf2f(hpu.x), bf2f(hpu.y), bf2f(hpu.z), bf2f(hpu.w) };
    float a0 = 0.f, a1 = 0.f, a2 = 0.f;
    #pragma unroll
    for (int u = 0; u < 4; ++u) {
        int c = lane * 4 + u;
        a0 = fmaf(hv[u], pp_wl[c * 3 + 0], a0);
        a1 = fmaf(hv[u], pp_wl[c * 3 + 1], a1);
        a2 = fmaf(hv[u], pp_wl[c * 3 + 2], a2);
    }
    #pragma unroll
    for (int m = 32; m; m >>= 1) {
        ad += __shfl_xor(ad, m);
        ae += __shfl_xor(ae, m);
        a0 += __shfl_xor(a0, m); a1 += __shfl_xor(a1, m); a2 += __shfl_xor(a2, m);
    }
    if (lane == 0) {
        float base = ad + dp_bl[0];
        float es = 0.8f + 0.4f * (nxn[row] / __uint_as_float(red[0]));
        int s = row & (S_ - 1);
        float ps = 1.0f + 0.1f * ((float)s * (1.f / (float)S_));
        float ld = base * es * ps;
        float d = expf(ld);
        o_logdur[row] = ld;
        o_dur[row] = d;
        durf[row] = d;
        float p0 = a0 + pp_bl[0], p1 = a1 + pp_bl[1], p2 = a2 + pp_bl[2];
        float mn = __uint_as_float(red[1]), mx = __uint_as_float(red[2]);
        float en = (nx[row] - mn) / (mx - mn + 1e-8f);
        float f0s = 100.f + 400.f * en;
        float f0b = expf(p0) * f0s * (1.f / 220.f);
        o_pitch[(size_t)row * 3 + 0] = logf(f0b + 1e-8f);
        o_pitch[(size_t)row * 3 + 1] = p1;
        o_pitch[(size_t)row * 3 + 2] = p2;
        o_energy[row] = ae + ep_bl[0];
    }
}

// ============================================================
// K6: per-batch round->cumsum->clip->searchsorted + mel mask
// ============================================================
__global__ __launch_bounds__(1024) void regulate_kernel(
    const float* __restrict__ durf, int* __restrict__ idxbuf, float* __restrict__ mask)
{
    __shared__ int cum[S_];
    int b = blockIdx.x;
    int t = threadIdx.x;
    int d = (int)rintf(durf[b * S_ + t]);
    cum[t] = d;
    __syncthreads();
    for (int off = 1; off < S_; off <<= 1) {
        int v = (t >= off) ? cum[t - off] : 0;
        __syncthreads();
        cum[t] += v;
        __syncthreads();
    }
    cum[t] = min(cum[t], T_);
    __syncthreads();
    int total = cum[S_ - 1];
    for (int t0 = t; t0 < T_; t0 += S_) {
        int lo = 0, hi = S_;
        while (lo < hi) {
            int mid = (lo + hi) >> 1;
            if (cum[mid] <= t0) lo = mid + 1; else hi = mid;
        }
        int id = min(lo, S_ - 1);
        bool masked = (t0 >= total);
        idxbuf[b * T_ + t0] = masked ? -1 : id;
        mask[(size_t)b * T_ + t0] = masked ? 1.f : 0.f;
    }
}

// ============================================================
// K7: expanded gather. 1 wave = 1 (b,t) row, float4/lane
// ============================================================
__global__ __launch_bounds__(256) void expand_kernel(
    const float* __restrict__ xp, const int* __restrict__ idxbuf, float* __restrict__ expd)
{
    int row = blockIdx.x * 4 + (threadIdx.x >> 6);
    int lane = threadIdx.x & 63;
    int id = idxbuf[row];
    int b = row >> 13;
    float4 v = make_float4(0.f, 0.f, 0.f, 0.f);
    if (id >= 0)
        v = ((const float4*)(xp + ((size_t)(b * S_ + id)) * D_))[lane];
    ((float4*)(expd + (size_t)row * D_))[lane] = v;
}

// ============================================================
extern "C" void kernel_launch(void* const* d_in, const int* in_sizes, int n_in,
                              void* d_out, int out_size, void* d_ws, size_t ws_size,
                              hipStream_t stream) {
    const float* x     = (const float*)d_in[0];
    const float* note  = (const float*)d_in[2];
    const float* ln_g  = (const float*)d_in[3];
    const float* ln_b  = (const float*)d_in[4];
    const float* dp_w1 = (const float*)d_in[5];
    const float* dp_b1 = (const float*)d_in[6];
    const float* dp_w2 = (const float*)d_in[7];
    const float* dp_b2 = (const float*)d_in[8];
    const float* dp_wl = (const float*)d_in[9];
    const float* dp_bl = (const float*)d_in[10];
    const float* pp_w1 = (const float*)d_in[11];
    const float* pp_b1 = (const float*)d_in[12];
    const float* pp_w2 = (const float*)d_in[13];
    const float* pp_b2 = (const float*)d_in[14];
    const float* pp_wl = (const float*)d_in[15];
    const float* pp_bl = (const float*)d_in[16];
    const float* ep_w1 = (const float*)d_in[17];
    const float* ep_b1 = (const float*)d_in[18];
    const float* ep_w2 = (const float*)d_in[19];
    const float* ep_b2 = (const float*)d_in[20];
    const float* ep_wl = (const float*)d_in[21];
    const float* ep_bl = (const float*)d_in[22];
    const float* np_w  = (const float*)d_in[23];
    const float* np_b  = (const float*)d_in[24];

    // d_out: logdur | dur | pitch | energy | expanded | melmask
    float* o_logdur = (float*)d_out;
    float* o_dur    = o_logdur + ROWS;
    float* o_pitch  = o_dur + ROWS;
    float* o_energy = o_pitch + ROWS * 3;
    float* o_exp    = o_energy + ROWS;
    float* o_mask   = o_exp + (size_t)B_ * T_ * D_;

    // intermediates inside the expanded region (rewritten last by expand)
    const size_t CH = (size_t)ROWS * D_;      // 4,194,304 floats
    float* h2_dp = o_exp + 0 * CH;
    unsigned short* h2_ppb  = (unsigned short*)(o_exp + 1 * CH);            // CH bf16
    unsigned short* h2_epb  = (unsigned short*)(o_exp + 1 * CH + CH / 2);   // CH bf16
    unsigned short* h1_ppb  = (unsigned short*)(o_exp + 2 * CH);            // CH bf16
    unsigned short* h1_epb  = (unsigned short*)(o_exp + 2 * CH + CH / 2);   // CH bf16
    unsigned short* xp_bf   = (unsigned short*)(o_exp + 3 * CH);            // CH bf16
    unsigned short* xn_hi   = (unsigned short*)(o_exp + 3 * CH + CH / 2);   // CH bf16
    unsigned short* xn_lo   = (unsigned short*)(o_exp + 4 * CH);            // CH bf16
    unsigned short* h1dp_hi = (unsigned short*)(o_exp + 4 * CH + CH / 2);   // CH bf16
    unsigned short* h1dp_lo = (unsigned short*)(o_exp + 5 * CH);            // CH bf16
    unsigned short* wt      = (unsigned short*)(o_exp + 5 * CH + CH / 2);   // 8*196608 bf16
    unsigned short* wt_pp1  = wt;
    unsigned short* wt_ep1  = wt + 196608;
    unsigned short* wt_pp2  = wt + 2 * 196608;
    unsigned short* wt_ep2  = wt + 3 * 196608;
    unsigned short* wt_dp1h = wt + 4 * 196608;
    unsigned short* wt_dp1l = wt + 5 * 196608;
    unsigned short* wt_dp2h = wt + 6 * 196608;
    unsigned short* wt_dp2l = wt + 7 * 196608;

    // d_ws: xprime | norm_xn | norm_x | red | durf | idxbuf
    float* ws_f    = (float*)d_ws;
    float* xprime  = ws_f;
    float* norm_xn = ws_f + CH;
    float* norm_x  = norm_xn + ROWS;
    unsigned* red  = (unsigned*)(norm_x + ROWS);
    float* durf    = (float*)(red + 4);
    int*   idxbuf  = (int*)(durf + ROWS);

    wprep_kernel<<<256, 256, 0, stream>>>(pp_w1, ep_w1, pp_w2, ep_w2, dp_w1, dp_w2, wt);
    noteproj_kernel<<<dim3(ROWS / 64, D_ / 64), 256, 0, stream>>>(x, note, np_w, np_b, xprime, red);
    rowstats_kernel<<<ROWS / 4, 256, 0, stream>>>(xprime, ln_g, ln_b, xn_hi, xn_lo, norm_xn, norm_x, xp_bf);
    reduce_fast_kernel<<<32, 256, 0, stream>>>(norm_xn, norm_x, red);

    dim3 cgrid(64, F_ / 64, 3);   // all-real blocks: 768 = 3/CU, fully resident
    ConvAll s1;
    s1.dp_in_hi = xn_hi;   s1.dp_in_lo = xn_lo;
    s1.dp_wt_hi = wt_dp1h; s1.dp_wt_lo = wt_dp1l;
    s1.dp_bias = dp_b1;
    s1.dp_out_hi = h1dp_hi; s1.dp_out_lo = h1dp_lo; s1.dp_out_f = nullptr;
    s1.inb[0] = xp_bf;  s1.wt[0] = wt_pp1; s1.bias[0] = pp_b1; s1.out[0] = h1_ppb;
    s1.inb[1] = xp_bf;  s1.wt[1] = wt_ep1; s1.bias[1] = ep_b1; s1.out[1] = h1_epb;
    s1.bfout = 1;
    convall_kernel<<<cgrid, 256, 0, stream>>>(s1);

    ConvAll s2;
    s2.dp_in_hi = h1dp_hi; s2.dp_in_lo = h1dp_lo;
    s2.dp_wt_hi = wt_dp2h; s2.dp_wt_lo = wt_dp2l;
    s2.dp_bias = dp_b2;
    s2.dp_out_hi = nullptr; s2.dp_out_lo = nullptr; s2.dp_out_f = h2_dp;
    s2.inb[0] = h1_ppb; s2.wt[0] = wt_pp2; s2.bias[0] = pp_b2; s2.out[0] = h2_ppb;
    s2.inb[1] = h1_epb; s2.wt[1] = wt_ep2; s2.bias[1] = ep_b2; s2.out[1] = h2_epb;
    s2.bfout = 0;
    convall_kernel<<<cgrid, 256, 0, stream>>>(s2);

    linfused_kernel<<<ROWS / 4, 256, 0, stream>>>(h2_dp, h2_ppb, h2_epb,
        dp_wl, dp_bl, pp_wl, pp_bl, ep_wl, ep_bl,
        norm_xn, norm_x, red, o_logdur, o_dur, durf, o_pitch, o_energy);

    regulate_kernel<<<B_, 1024, 0, stream>>>(durf, idxbuf, o_mask);
    expand_kernel<<<(B_ * T_) / 4, 256, 0, stream>>>(xprime, idxbuf, o_exp);
}

// Round 12
// 390.224 us; speedup vs baseline: 1.0494x; 1.0164x over previous
//
#include <hip/hip_runtime.h>
#include <math.h>

#define B_ 16
#define S_ 1024
#define D_ 256
#define F_ 256
#define T_ 8192
#define ROWS (B_ * S_)  // 16384

typedef __attribute__((ext_vector_type(8))) short short8x;
typedef __attribute__((ext_vector_type(4))) float f32x4;

static __device__ __forceinline__ unsigned short f2bf(float f) {
    unsigned u = __float_as_uint(f);
    unsigned r = (u + 0x7FFFu + ((u >> 16) & 1u)) >> 16;  // round-to-nearest-even
    return (unsigned short)r;
}
static __device__ __forceinline__ float bf2f(unsigned short h) {
    return __uint_as_float(((unsigned)h) << 16);
}

// ============================================================
// K0: weight prep -> FRAGMENT-ORDER layout (R8-exact).
// Tensors: t0..3 = pp1,ep1,pp2,ep2 (plain bf16); t4..7 = dp1h,dp1l,dp2h,dp2l
// ============================================================
__global__ __launch_bounds__(256) void wprep_kernel(
    const float* __restrict__ pw1, const float* __restrict__ ew1,
    const float* __restrict__ pw2, const float* __restrict__ ew2,
    const float* __restrict__ dw1, const float* __restrict__ dw2,
    unsigned short* __restrict__ wt)
{
    int idx = blockIdx.x * 256 + threadIdx.x;   // 0..65535 -> (o, c)
    int o = idx >> 8, c = idx & 255;
    int o_t = o >> 6, nt = (o >> 4) & 3, lr = o & 15;
    int cbk = c >> 5, hs = (c >> 3) & 3, j = c & 7;
    int lane = hs * 16 + lr;
    size_t fbase = ((size_t)o_t * 8 + cbk) * 3;   // *k later

    const float* srcs[4] = { pw1, ew1, pw2, ew2 };
    #pragma unroll
    for (int t = 0; t < 4; ++t) {
        const float* p = srcs[t] + ((size_t)o * 256 + c) * 3;
        unsigned short* dst = wt + (size_t)t * 196608;
        #pragma unroll
        for (int k = 0; k < 3; ++k) {
            size_t off = (((fbase + k) * 4 + nt) * 64 + lane) * 8 + j;
            dst[off] = f2bf(p[k]);
        }
    }
    const float* dsrc[2] = { dw1, dw2 };
    #pragma unroll
    for (int t = 0; t < 2; ++t) {
        const float* p = dsrc[t] + ((size_t)o * 256 + c) * 3;
        unsigned short* dh = wt + (size_t)(4 + 2 * t) * 196608;
        unsigned short* dl = dh + 196608;
        #pragma unroll
        for (int k = 0; k < 3; ++k) {
            size_t off = (((fbase + k) * 4 + nt) * 64 + lane) * 8 + j;
            float v = p[k];
            unsigned short hi = f2bf(v);
            dh[off] = hi;
            dl[off] = f2bf(v - bf2f(hi));
        }
    }
}

// ============================================================
// K1: x' = x + note_pitch @ np_w + np_b  (R8-exact fp32 LDS GEMM)
// ============================================================
__global__ __launch_bounds__(256) void noteproj_kernel(
    const float* __restrict__ x, const float* __restrict__ note,
    const float* __restrict__ w, const float* __restrict__ bias,
    float* __restrict__ xp, unsigned* __restrict__ red)
{
    if (blockIdx.x == 0 && blockIdx.y == 0 && threadIdx.x == 0) {
        red[0] = 0u;            // max ||xn||
        red[1] = 0x7F7FFFFFu;   // min ||x'||  (FLT_MAX bits)
        red[2] = 0u;            // max ||x'||
    }
    __shared__ float As[16][66];
    __shared__ float Bs[16][68];
    const int tid = threadIdx.x;
    const int m0 = blockIdx.x << 6;
    const int o0 = blockIdx.y << 6;
    const int tc = tid & 15, tr = tid >> 4;
    const int r = tr << 2, oc = tc << 2;
    const int tA = tid >> 2, cg = (tid & 3) << 2;
    const int cB = tid >> 4, oB = (tid & 15) << 2;
    float acc[4][4] = {};

    for (int c0 = 0; c0 < D_; c0 += 16) {
        float4 av = *(const float4*)(note + (size_t)(m0 + tA) * D_ + c0 + cg);
        As[cg + 0][tA] = av.x; As[cg + 1][tA] = av.y;
        As[cg + 2][tA] = av.z; As[cg + 3][tA] = av.w;
        *(float4*)&Bs[cB][oB] = *(const float4*)(w + (size_t)(c0 + cB) * D_ + o0 + oB);
        __syncthreads();
        #pragma unroll
        for (int c = 0; c < 16; ++c) {
            float a[4], bv[4];
            #pragma unroll
            for (int m = 0; m < 4; ++m) a[m] = As[c][r + m];
            #pragma unroll
            for (int j = 0; j < 4; ++j) bv[j] = Bs[c][oc + j];
            #pragma unroll
            for (int i = 0; i < 4; ++i)
                #pragma unroll
                for (int j = 0; j < 4; ++j)
                    acc[i][j] = fmaf(a[i], bv[j], acc[i][j]);
        }
        __syncthreads();
    }
    #pragma unroll
    for (int i = 0; i < 4; ++i) {
        size_t row = (size_t)(m0 + r + i);
        const float* xr = x + row * D_ + o0 + oc;
        float4 v;
        v.x = acc[i][0] + bias[o0 + oc + 0] + xr[0];
        v.y = acc[i][1] + bias[o0 + oc + 1] + xr[1];
        v.z = acc[i][2] + bias[o0 + oc + 2] + xr[2];
        v.w = acc[i][3] + bias[o0 + oc + 3] + xr[3];
        *(float4*)(xp + row * D_ + o0 + oc) = v;
    }
}

// ============================================================
// K2: layernorm + norms + bf16 copies. 1 wave = 1 row.
// ============================================================
__global__ __launch_bounds__(256) void rowstats_kernel(
    const float* __restrict__ xp, const float* __restrict__ g, const float* __restrict__ bb,
    unsigned short* __restrict__ xnh, unsigned short* __restrict__ xnl,
    float* __restrict__ nxn, float* __restrict__ nx,
    unsigned short* __restrict__ xpb)
{
    int row = blockIdx.x * 4 + (threadIdx.x >> 6);
    int lane = threadIdx.x & 63;
    float4 v = ((const float4*)(xp + (size_t)row * D_))[lane];
    ushort4 bv4;
    bv4.x = f2bf(v.x); bv4.y = f2bf(v.y); bv4.z = f2bf(v.z); bv4.w = f2bf(v.w);
    ((ushort4*)xpb)[(size_t)row * 64 + lane] = bv4;

    float s = v.x + v.y + v.z + v.w;
    float sq = v.x * v.x + v.y * v.y + v.z * v.z + v.w * v.w;
    #pragma unroll
    for (int m = 32; m; m >>= 1) { s += __shfl_xor(s, m); sq += __shfl_xor(sq, m); }
    float mean = s * (1.f / 256.f);
    float var = sq * (1.f / 256.f) - mean * mean;
    float rs = rsqrtf(var + 1e-5f);
    float4 gv = ((const float4*)g)[lane];
    float4 bv = ((const float4*)bb)[lane];
    float4 o;
    o.x = gv.x * (v.x - mean) * rs + bv.x;
    o.y = gv.y * (v.y - mean) * rs + bv.y;
    o.z = gv.z * (v.z - mean) * rs + bv.z;
    o.w = gv.w * (v.w - mean) * rs + bv.w;
    ushort4 h4, l4;
    h4.x = f2bf(o.x); l4.x = f2bf(o.x - bf2f(h4.x));
    h4.y = f2bf(o.y); l4.y = f2bf(o.y - bf2f(h4.y));
    h4.z = f2bf(o.z); l4.z = f2bf(o.z - bf2f(h4.z));
    h4.w = f2bf(o.w); l4.w = f2bf(o.w - bf2f(h4.w));
    ((ushort4*)xnh)[(size_t)row * 64 + lane] = h4;
    ((ushort4*)xnl)[(size_t)row * 64 + lane] = l4;

    float q = o.x * o.x + o.y * o.y + o.z * o.z + o.w * o.w;
    #pragma unroll
    for (int m = 32; m; m >>= 1) q += __shfl_xor(q, m);
    if (lane == 0) { nxn[row] = sqrtf(q); nx[row] = sqrtf(sq); }
}

// ============================================================
// K3: fast global reduce via uint-monotonic atomics (positive floats)
// ============================================================
__global__ __launch_bounds__(256) void reduce_fast_kernel(
    const float* __restrict__ nxn, const float* __restrict__ nx, unsigned* __restrict__ red)
{
    int tid = threadIdx.x;
    int lane = tid & 63, wave = tid >> 6;
    float mxn = 0.f, mnx = 3.0e38f, mxx = 0.f;
    for (int i = blockIdx.x * 256 + tid; i < ROWS; i += 32 * 256) {
        mxn = fmaxf(mxn, nxn[i]);
        float v = nx[i];
        mnx = fminf(mnx, v);
        mxx = fmaxf(mxx, v);
    }
    #pragma unroll
    for (int m = 32; m; m >>= 1) {
        mxn = fmaxf(mxn, __shfl_xor(mxn, m));
        mnx = fminf(mnx, __shfl_xor(mnx, m));
        mxx = fmaxf(mxx, __shfl_xor(mxx, m));
    }
    __shared__ float a0[4], a1[4], a2[4];
    if (lane == 0) { a0[wave] = mxn; a1[wave] = mnx; a2[wave] = mxx; }
    __syncthreads();
    if (tid == 0) {
        #pragma unroll
        for (int w2 = 1; w2 < 4; ++w2) {
            mxn = fmaxf(mxn, a0[w2]); mnx = fminf(mnx, a1[w2]); mxx = fmaxf(mxx, a2[w2]);
        }
        atomicMax(&red[0], __float_as_uint(mxn));
        atomicMin(&red[1], __float_as_uint(mnx));
        atomicMax(&red[2], __float_as_uint(mxx));
    }
}

// ============================================================
// K4: LDS-free conv stage (R11 structure, grid (64,4,3) all-real).
// NEW vs R11: dots==1 (stage 2) fuses the final 1x1 linears — each
// wave reduces its 64x64 tile to per-row partial dots via 16-lane
// shuffle butterflies and writes [y][row] partials (1.3MB) instead
// of materializing h2 (33MB). Stage 1 (dots==0) byte-identical.
// ============================================================
struct ConvAll {
    const unsigned short* dp_in_hi; const unsigned short* dp_in_lo;   // [B*S][256]
    const unsigned short* dp_wt_hi; const unsigned short* dp_wt_lo;   // frag-order
    const float* dp_bias;
    unsigned short* dp_out_hi; unsigned short* dp_out_lo;  // stage1 dp out
    const unsigned short* inb[2];
    const unsigned short* wt[2];     // frag-order
    const float* bias[2];
    unsigned short* out[2];          // stage1 pp/ep outputs (bf16)
    // stage-2 fused-dot outputs
    float* pd_dp;                    // [4][ROWS]
    float* pd_pp;                    // [4][ROWS][3]
    float* pd_ep;                    // [4][ROWS]
    const float* wl_dp; const float* wl_pp; const float* wl_ep;
    int dots;                        // 0 = stage1 epilogues, 1 = fused dots
};

__global__ __launch_bounds__(256) void convall_kernel(ConvAll cb)
{
    __shared__ __align__(16) char smem[36864];   // 128 x 72 epilogue buffer (stage1)
    const int tid = threadIdx.x;
    const int z = blockIdx.z;
    const int o0 = blockIdx.y << 6;
    const int wave = tid >> 6, lane = tid & 63;
    const int lm = lane & 15, lk8 = (lane >> 4) << 3;
    const int q4 = (lane >> 4) << 2;
    const int b = blockIdx.x >> 2;
    const int S0 = (blockIdx.x & 3) << 8;   // 0,256,512,768
    const int wr = wave << 6;               // wave's first row (0,64,128,192)

    if (z == 0) {
        // ---------------- dp split-bf16 path: 256-row tile, 64 rows/wave ----------------
        f32x4 acc[4][4] = {};
        unsigned aoff[4][3]; bool aok[4][3];
        #pragma unroll
        for (int st = 0; st < 4; ++st)
            #pragma unroll
            for (int k = 0; k < 3; ++k) {
                int srow = S0 + wr + (st << 4) + lm + k - 1;
                aok[st][k] = (srow >= 0) && (srow < S_);
                int sr = srow < 0 ? 0 : (srow >= S_ ? S_ - 1 : srow);
                aoff[st][k] = (unsigned)(b * S_ + sr) * D_ + lk8;
            }
        const unsigned short* ih = cb.dp_in_hi;
        const unsigned short* il = cb.dp_in_lo;
        const unsigned short* wh = cb.dp_wt_hi + (size_t)(o0 >> 6) * 49152 + (size_t)lane * 8;
        const unsigned short* wl = cb.dp_wt_lo + (size_t)(o0 >> 6) * 49152 + (size_t)lane * 8;
        for (int c0 = 0; c0 < D_; c0 += 32) {
            const int cbi = c0 >> 5;
            #pragma unroll
            for (int k = 0; k < 3; ++k) {
                uint4 ah4[4], al4[4];
                #pragma unroll
                for (int st = 0; st < 4; ++st) {
                    uint4 vh = make_uint4(0u, 0u, 0u, 0u);
                    uint4 vl = make_uint4(0u, 0u, 0u, 0u);
                    if (aok[st][k]) {
                        unsigned off = aoff[st][k] + c0;
                        vh = *(const uint4*)(const void*)(ih + off);
                        vl = *(const uint4*)(const void*)(il + off);
                    }
                    ah4[st] = vh; al4[st] = vl;
                }
                const unsigned short* bph = wh + (size_t)((cbi * 3 + k) * 4) * 512;
                const unsigned short* bpl = wl + (size_t)((cbi * 3 + k) * 4) * 512;
                #pragma unroll
                for (int nt = 0; nt < 4; ++nt) {
                    short8x bh = *(const short8x*)(const void*)(bph + nt * 512);
                    short8x bl = *(const short8x*)(const void*)(bpl + nt * 512);
                    #pragma unroll
                    for (int st = 0; st < 4; ++st) {
                        short8x ah = *(short8x*)&ah4[st];
                        short8x al = *(short8x*)&al4[st];
                        acc[st][nt] = __builtin_amdgcn_mfma_f32_16x16x32_bf16(ah, bh, acc[st][nt], 0, 0, 0);
                        acc[st][nt] = __builtin_amdgcn_mfma_f32_16x16x32_bf16(ah, bl, acc[st][nt], 0, 0, 0);
                        acc[st][nt] = __builtin_amdgcn_mfma_f32_16x16x32_bf16(al, bh, acc[st][nt], 0, 0, 0);
                    }
                }
            }
        }
        float bvv[4];
        #pragma unroll
        for (int nt = 0; nt < 4; ++nt) bvv[nt] = cb.dp_bias[o0 + (nt << 4) + lm];
        if (cb.dots) {
            // ---- fused dp dot: per-row partial over this 64-col chunk ----
            float wld[4];
            #pragma unroll
            for (int nt = 0; nt < 4; ++nt) wld[nt] = cb.wl_dp[o0 + (nt << 4) + lm];
            float* pout = cb.pd_dp + (size_t)blockIdx.y * ROWS + (size_t)(b * S_ + S0 + wr);
            #pragma unroll
            for (int st = 0; st < 4; ++st)
                #pragma unroll
                for (int rg = 0; rg < 4; ++rg) {
                    float s = 0.f;
                    #pragma unroll
                    for (int nt = 0; nt < 4; ++nt)
                        s = fmaf(fmaxf(acc[st][nt][rg] + bvv[nt], 0.f), wld[nt], s);
                    s += __shfl_xor(s, 1); s += __shfl_xor(s, 2);
                    s += __shfl_xor(s, 4); s += __shfl_xor(s, 8);
                    if (lm == 0) pout[(st << 4) + q4 + rg] = s;
                }
        } else {
            // ---- stage-1 dp epilogue: hi/lo pair (R11-exact) ----
            const int hw = wr >> 7, base = wr & 127;
            unsigned short* L = (unsigned short*)smem;           // [128][72] ushorts
            #pragma unroll
            for (int pass = 0; pass < 2; ++pass) {
                unsigned short* outp = pass ? cb.dp_out_lo : cb.dp_out_hi;
                #pragma unroll
                for (int h = 0; h < 2; ++h) {
                    if (pass | h) __syncthreads();
                    if (hw == h) {
                        #pragma unroll
                        for (int nt = 0; nt < 4; ++nt)
                            #pragma unroll
                            for (int st = 0; st < 4; ++st)
                                #pragma unroll
                                for (int rg = 0; rg < 4; ++rg) {
                                    int lrow = base + (st << 4) + q4 + rg;
                                    int lcol = (nt << 4) + lm;
                                    float v = fmaxf(acc[st][nt][rg] + bvv[nt], 0.f);
                                    unsigned short hi = f2bf(v);
                                    L[lrow * 72 + lcol] = pass ? f2bf(v - bf2f(hi)) : hi;
                                }
                    }
                    __syncthreads();
                    #pragma unroll
                    for (int q = 0; q < 4; ++q) {
                        int flat = (q << 8) + tid;
                        int rrow = flat >> 3, u = flat & 7;
                        uint4 val = *(const uint4*)(const void*)&L[rrow * 72 + (u << 3)];
                        *(uint4*)(void*)(outp + ((size_t)(b * S_ + S0 + (h << 7) + rrow)) * D_ + o0 + (u << 3)) = val;
                    }
                }
            }
        }
    } else {
        // ---------------- pp/ep path: 256-row tile, 64 rows/wave ----------------
        const int z1 = z - 1;
        f32x4 acc[4][4] = {};
        unsigned aoff[4][3]; bool aok[4][3];
        #pragma unroll
        for (int st = 0; st < 4; ++st)
            #pragma unroll
            for (int k = 0; k < 3; ++k) {
                int srow = S0 + wr + (st << 4) + lm + k - 1;
                aok[st][k] = (srow >= 0) && (srow < S_);
                int sr = srow < 0 ? 0 : (srow >= S_ ? S_ - 1 : srow);
                aoff[st][k] = (unsigned)(b * S_ + sr) * D_ + lk8;
            }
        const unsigned short* inp = cb.inb[z1];
        const unsigned short* wp = cb.wt[z1] + (size_t)(o0 >> 6) * 49152 + (size_t)lane * 8;
        for (int c0 = 0; c0 < D_; c0 += 32) {
            const int cbi = c0 >> 5;
            uint4 pa[4][3];
            #pragma unroll
            for (int st = 0; st < 4; ++st)
                #pragma unroll
                for (int k = 0; k < 3; ++k) {
                    uint4 v = make_uint4(0u, 0u, 0u, 0u);
                    if (aok[st][k]) v = *(const uint4*)(const void*)(inp + aoff[st][k] + c0);
                    pa[st][k] = v;
                }
            #pragma unroll
            for (int k = 0; k < 3; ++k) {
                const unsigned short* bp = wp + (size_t)((cbi * 3 + k) * 4) * 512;
                short8x a0 = *(short8x*)&pa[0][k];
                short8x a1 = *(short8x*)&pa[1][k];
                short8x a2 = *(short8x*)&pa[2][k];
                short8x a3 = *(short8x*)&pa[3][k];
                #pragma unroll
                for (int nt = 0; nt < 4; ++nt) {
                    short8x bf = *(const short8x*)(const void*)(bp + nt * 512);
                    acc[0][nt] = __builtin_amdgcn_mfma_f32_16x16x32_bf16(a0, bf, acc[0][nt], 0, 0, 0);
                    acc[1][nt] = __builtin_amdgcn_mfma_f32_16x16x32_bf16(a1, bf, acc[1][nt], 0, 0, 0);
                    acc[2][nt] = __builtin_amdgcn_mfma_f32_16x16x32_bf16(a2, bf, acc[2][nt], 0, 0, 0);
                    acc[3][nt] = __builtin_amdgcn_mfma_f32_16x16x32_bf16(a3, bf, acc[3][nt], 0, 0, 0);
                }
            }
        }
        float bvv[4];
        #pragma unroll
        for (int nt = 0; nt < 4; ++nt) bvv[nt] = cb.bias[z1][o0 + (nt << 4) + lm];
        if (cb.dots) {
            if (z1 == 0) {
                // ---- fused pp dots (3 outputs) ----
                float w0[4], w1[4], w2[4];
                #pragma unroll
                for (int nt = 0; nt < 4; ++nt) {
                    int c = o0 + (nt << 4) + lm;
                    w0[nt] = cb.wl_pp[c * 3 + 0];
                    w1[nt] = cb.wl_pp[c * 3 + 1];
                    w2[nt] = cb.wl_pp[c * 3 + 2];
                }
                float* pout = cb.pd_pp + ((size_t)blockIdx.y * ROWS + (size_t)(b * S_ + S0 + wr)) * 3;
                #pragma unroll
                for (int st = 0; st < 4; ++st)
                    #pragma unroll
                    for (int rg = 0; rg < 4; ++rg) {
                        float s0 = 0.f, s1 = 0.f, s2 = 0.f;
                        #pragma unroll
                        for (int nt = 0; nt < 4; ++nt) {
                            float v = fmaxf(acc[st][nt][rg] + bvv[nt], 0.f);
                            s0 = fmaf(v, w0[nt], s0);
                            s1 = fmaf(v, w1[nt], s1);
                            s2 = fmaf(v, w2[nt], s2);
                        }
                        #pragma unroll
                        for (int m = 1; m < 16; m <<= 1) {
                            s0 += __shfl_xor(s0, m);
                            s1 += __shfl_xor(s1, m);
                            s2 += __shfl_xor(s2, m);
                        }
                        if (lm == 0) {
                            size_t o = (size_t)((st << 4) + q4 + rg) * 3;
                            pout[o + 0] = s0; pout[o + 1] = s1; pout[o + 2] = s2;
                        }
                    }
            } else {
                // ---- fused ep dot ----
                float wld[4];
                #pragma unroll
                for (int nt = 0; nt < 4; ++nt) wld[nt] = cb.wl_ep[o0 + (nt << 4) + lm];
                float* pout = cb.pd_ep + (size_t)blockIdx.y * ROWS + (size_t)(b * S_ + S0 + wr);
                #pragma unroll
                for (int st = 0; st < 4; ++st)
                    #pragma unroll
                    for (int rg = 0; rg < 4; ++rg) {
                        float s = 0.f;
                        #pragma unroll
                        for (int nt = 0; nt < 4; ++nt)
                            s = fmaf(fmaxf(acc[st][nt][rg] + bvv[nt], 0.f), wld[nt], s);
                        s += __shfl_xor(s, 1); s += __shfl_xor(s, 2);
                        s += __shfl_xor(s, 4); s += __shfl_xor(s, 8);
                        if (lm == 0) pout[(st << 4) + q4 + rg] = s;
                    }
            }
        } else {
            // ---- stage-1 pp/ep epilogue: bf16, two 128-row passes (R11-exact) ----
            const int hw = wr >> 7, base = wr & 127;
            unsigned short* L = (unsigned short*)smem;           // [128][72] ushorts
            unsigned short* outp = cb.out[z1];
            #pragma unroll
            for (int h = 0; h < 2; ++h) {
                if (h) __syncthreads();
                if (hw == h) {
                    #pragma unroll
                    for (int nt = 0; nt < 4; ++nt)
                        #pragma unroll
                        for (int st = 0; st < 4; ++st)
                            #pragma unroll
                            for (int rg = 0; rg < 4; ++rg) {
                                int lrow = base + (st << 4) + q4 + rg;
                                int lcol = (nt << 4) + lm;
                                L[lrow * 72 + lcol] = f2bf(fmaxf(acc[st][nt][rg] + bvv[nt], 0.f));
                            }
                }
                __syncthreads();
                #pragma unroll
                for (int q = 0; q < 4; ++q) {
                    int flat = (q << 8) + tid;
                    int rrow = flat >> 3, u = flat & 7;
                    uint4 val = *(const uint4*)(const void*)&L[rrow * 72 + (u << 3)];
                    *(uint4*)(void*)(outp + ((size_t)(b * S_ + S0 + (h << 7) + rrow)) * D_ + o0 + (u << 3)) = val;
                }
            }
        }
    }
}

// ============================================================
// K5: finalize — sum 4 y-partials IN FIXED ORDER (deterministic),
// apply the duration/pitch/energy epilogues. 1 thread = 1 row.
// ============================================================
__global__ __launch_bounds__(256) void finalize_kernel(
    const float* __restrict__ pd_dp, const float* __restrict__ pd_pp,
    const float* __restrict__ pd_ep,
    const float* __restrict__ dp_bl, const float* __restrict__ pp_bl,
    const float* __restrict__ ep_bl,
    const float* __restrict__ nxn, const float* __restrict__ nx, const unsigned* __restrict__ red,
    float* __restrict__ o_logdur, float* __restrict__ o_dur, float* __restrict__ durf,
    float* __restrict__ o_pitch, float* __restrict__ o_energy)
{
    int row = blockIdx.x * 256 + threadIdx.x;
    float ad = ((pd_dp[row] + pd_dp[ROWS + row]) + pd_dp[2 * ROWS + row]) + pd_dp[3 * ROWS + row];
    float ae = ((pd_ep[row] + pd_ep[ROWS + row]) + pd_ep[2 * ROWS + row]) + pd_ep[3 * ROWS + row];
    float a0 = 0.f, a1 = 0.f, a2 = 0.f;
    #pragma unroll
    for (int y = 0; y < 4; ++y) {
        size_t o = ((size_t)y * ROWS + row) * 3;
        a0 += pd_pp[o + 0]; a1 += pd_pp[o + 1]; a2 += pd_pp[o + 2];
    }
    // duration epilogue
    float base = ad + dp_bl[0];
    float es = 0.8f + 0.4f * (nxn[row] / __uint_as_float(red[0]));
    int s = row & (S_ - 1);
    float ps = 1.0f + 0.1f * ((float)s * (1.f / (float)S_));
    float ld = base * es * ps;
    float d = expf(ld);
    o_logdur[row] = ld;
    o_dur[row] = d;
    durf[row] = d;
    // pitch epilogue
    float p0 = a0 + pp_bl[0], p1 = a1 + pp_bl[1], p2 = a2 + pp_bl[2];
    float mn = __uint_as_float(red[1]), mx = __uint_as_float(red[2]);
    float en = (nx[row] - mn) / (mx - mn + 1e-8f);
    float f0s = 100.f + 400.f * en;
    float f0b = expf(p0) * f0s * (1.f / 220.f);
    o_pitch[(size_t)row * 3 + 0] = logf(f0b + 1e-8f);
    o_pitch[(size_t)row * 3 + 1] = p1;
    o_pitch[(size_t)row * 3 + 2] = p2;
    // energy
    o_energy[row] = ae + ep_bl[0];
}

// ============================================================
// K6: per-batch round->cumsum->clip->searchsorted + mel mask
// ============================================================
__global__ __launch_bounds__(1024) void regulate_kernel(
    const float* __restrict__ durf, int* __restrict__ idxbuf, float* __restrict__ mask)
{
    __shared__ int cum[S_];
    int b = blockIdx.x;
    int t = threadIdx.x;
    int d = (int)rintf(durf[b * S_ + t]);
    cum[t] = d;
    __syncthreads();
    for (int off = 1; off < S_; off <<= 1) {
        int v = (t >= off) ? cum[t - off] : 0;
        __syncthreads();
        cum[t] += v;
        __syncthreads();
    }
    cum[t] = min(cum[t], T_);
    __syncthreads();
    int total = cum[S_ - 1];
    for (int t0 = t; t0 < T_; t0 += S_) {
        int lo = 0, hi = S_;
        while (lo < hi) {
            int mid = (lo + hi) >> 1;
            if (cum[mid] <= t0) lo = mid + 1; else hi = mid;
        }
        int id = min(lo, S_ - 1);
        bool masked = (t0 >= total);
        idxbuf[b * T_ + t0] = masked ? -1 : id;
        mask[(size_t)b * T_ + t0] = masked ? 1.f : 0.f;
    }
}

// ============================================================
// K7: expanded gather. 1 wave = 1 (b,t) row, float4/lane
// ============================================================
__global__ __launch_bounds__(256) void expand_kernel(
    const float* __restrict__ xp, const int* __restrict__ idxbuf, float* __restrict__ expd)
{
    int row = blockIdx.x * 4 + (threadIdx.x >> 6);
    int lane = threadIdx.x & 63;
    int id = idxbuf[row];
    int b = row >> 13;
    float4 v = make_float4(0.f, 0.f, 0.f, 0.f);
    if (id >= 0)
        v = ((const float4*)(xp + ((size_t)(b * S_ + id)) * D_))[lane];
    ((float4*)(expd + (size_t)row * D_))[lane] = v;
}

// ============================================================
extern "C" void kernel_launch(void* const* d_in, const int* in_sizes, int n_in,
                              void* d_out, int out_size, void* d_ws, size_t ws_size,
                              hipStream_t stream) {
    const float* x     = (const float*)d_in[0];
    const float* note  = (const float*)d_in[2];
    const float* ln_g  = (const float*)d_in[3];
    const float* ln_b  = (const float*)d_in[4];
    const float* dp_w1 = (const float*)d_in[5];
    const float* dp_b1 = (const float*)d_in[6];
    const float* dp_w2 = (const float*)d_in[7];
    const float* dp_b2 = (const float*)d_in[8];
    const float* dp_wl = (const float*)d_in[9];
    const float* dp_bl = (const float*)d_in[10];
    const float* pp_w1 = (const float*)d_in[11];
    const float* pp_b1 = (const float*)d_in[12];
    const float* pp_w2 = (const float*)d_in[13];
    const float* pp_b2 = (const float*)d_in[14];
    const float* pp_wl = (const float*)d_in[15];
    const float* pp_bl = (const float*)d_in[16];
    const float* ep_w1 = (const float*)d_in[17];
    const float* ep_b1 = (const float*)d_in[18];
    const float* ep_w2 = (const float*)d_in[19];
    const float* ep_b2 = (const float*)d_in[20];
    const float* ep_wl = (const float*)d_in[21];
    const float* ep_bl = (const float*)d_in[22];
    const float* np_w  = (const float*)d_in[23];
    const float* np_b  = (const float*)d_in[24];

    // d_out: logdur | dur | pitch | energy | expanded | melmask
    float* o_logdur = (float*)d_out;
    float* o_dur    = o_logdur + ROWS;
    float* o_pitch  = o_dur + ROWS;
    float* o_energy = o_pitch + ROWS * 3;
    float* o_exp    = o_energy + ROWS;
    float* o_mask   = o_exp + (size_t)B_ * T_ * D_;

    // intermediates inside the expanded region (rewritten last by expand)
    const size_t CH = (size_t)ROWS * D_;      // 4,194,304 floats
    // stage-2 partial-dot buffers (replace h2 planes): 20*ROWS floats ~ 1.3MB
    float* pd_dp = o_exp;                     // [4][ROWS]
    float* pd_pp = o_exp + 4 * ROWS;          // [4][ROWS][3]
    float* pd_ep = o_exp + 16 * ROWS;         // [4][ROWS]
    unsigned short* h1_ppb  = (unsigned short*)(o_exp + 2 * CH);            // CH bf16
    unsigned short* h1_epb  = (unsigned short*)(o_exp + 2 * CH + CH / 2);   // CH bf16
    unsigned short* xp_bf   = (unsigned short*)(o_exp + 3 * CH);            // CH bf16
    unsigned short* xn_hi   = (unsigned short*)(o_exp + 3 * CH + CH / 2);   // CH bf16
    unsigned short* xn_lo   = (unsigned short*)(o_exp + 4 * CH);            // CH bf16
    unsigned short* h1dp_hi = (unsigned short*)(o_exp + 4 * CH + CH / 2);   // CH bf16
    unsigned short* h1dp_lo = (unsigned short*)(o_exp + 5 * CH);            // CH bf16
    unsigned short* wt      = (unsigned short*)(o_exp + 5 * CH + CH / 2);   // 8*196608 bf16
    unsigned short* wt_pp1  = wt;
    unsigned short* wt_ep1  = wt + 196608;
    unsigned short* wt_pp2  = wt + 2 * 196608;
    unsigned short* wt_ep2  = wt + 3 * 196608;
    unsigned short* wt_dp1h = wt + 4 * 196608;
    unsigned short* wt_dp1l = wt + 5 * 196608;
    unsigned short* wt_dp2h = wt + 6 * 196608;
    unsigned short* wt_dp2l = wt + 7 * 196608;

    // d_ws: xprime | norm_xn | norm_x | red | durf | idxbuf
    float* ws_f    = (float*)d_ws;
    float* xprime  = ws_f;
    float* norm_xn = ws_f + CH;
    float* norm_x  = norm_xn + ROWS;
    unsigned* red  = (unsigned*)(norm_x + ROWS);
    float* durf    = (float*)(red + 4);
    int*   idxbuf  = (int*)(durf + ROWS);

    wprep_kernel<<<256, 256, 0, stream>>>(pp_w1, ep_w1, pp_w2, ep_w2, dp_w1, dp_w2, wt);
    noteproj_kernel<<<dim3(ROWS / 64, D_ / 64), 256, 0, stream>>>(x, note, np_w, np_b, xprime, red);
    rowstats_kernel<<<ROWS / 4, 256, 0, stream>>>(xprime, ln_g, ln_b, xn_hi, xn_lo, norm_xn, norm_x, xp_bf);
    reduce_fast_kernel<<<32, 256, 0, stream>>>(norm_xn, norm_x, red);

    dim3 cgrid(64, F_ / 64, 3);   // all-real blocks: 768 = 3/CU, fully resident
    ConvAll s1;
    s1.dp_in_hi = xn_hi;   s1.dp_in_lo = xn_lo;
    s1.dp_wt_hi = wt_dp1h; s1.dp_wt_lo = wt_dp1l;
    s1.dp_bias = dp_b1;
    s1.dp_out_hi = h1dp_hi; s1.dp_out_lo = h1dp_lo;
    s1.inb[0] = xp_bf;  s1.wt[0] = wt_pp1; s1.bias[0] = pp_b1; s1.out[0] = h1_ppb;
    s1.inb[1] = xp_bf;  s1.wt[1] = wt_ep1; s1.bias[1] = ep_b1; s1.out[1] = h1_epb;
    s1.pd_dp = nullptr; s1.pd_pp = nullptr; s1.pd_ep = nullptr;
    s1.wl_dp = nullptr; s1.wl_pp = nullptr; s1.wl_ep = nullptr;
    s1.dots = 0;
    convall_kernel<<<cgrid, 256, 0, stream>>>(s1);

    ConvAll s2;
    s2.dp_in_hi = h1dp_hi; s2.dp_in_lo = h1dp_lo;
    s2.dp_wt_hi = wt_dp2h; s2.dp_wt_lo = wt_dp2l;
    s2.dp_bias = dp_b2;
    s2.dp_out_hi = nullptr; s2.dp_out_lo = nullptr;
    s2.inb[0] = h1_ppb; s2.wt[0] = wt_pp2; s2.bias[0] = pp_b2; s2.out[0] = nullptr;
    s2.inb[1] = h1_epb; s2.wt[1] = wt_ep2; s2.bias[1] = ep_b2; s2.out[1] = nullptr;
    s2.pd_dp = pd_dp; s2.pd_pp = pd_pp; s2.pd_ep = pd_ep;
    s2.wl_dp = dp_wl; s2.wl_pp = pp_wl; s2.wl_ep = ep_wl;
    s2.dots = 1;
    convall_kernel<<<cgrid, 256, 0, stream>>>(s2);

    finalize_kernel<<<ROWS / 256, 256, 0, stream>>>(pd_dp, pd_pp, pd_ep,
        dp_bl, pp_bl, ep_bl, norm_xn, norm_x, red,
        o_logdur, o_dur, durf, o_pitch, o_energy);

    regulate_kernel<<<B_, 1024, 0, stream>>>(durf, idxbuf, o_mask);
    expand_kernel<<<(B_ * T_) / 4, 256, 0, stream>>>(xprime, idxbuf, o_exp);
}